// Round 1
// baseline (2856.904 us; speedup 1.0000x reference)
//
#include <hip/hip_runtime.h>
#include <math.h>

// GINO forward, full-f32 (f64 embeds/twiddles). Sizes fixed by setup_inputs().
#define N_IN   100000
#define N_LQ   32768
#define N_OUT  30000
#define KNB    10

// -------- helpers --------
__device__ __forceinline__ float gelu_f(float x){
  // jax.nn.gelu approximate=True: 0.5x(1+tanh(sqrt(2/pi)(x+0.044715x^3)))
  float t = 0.79788456080286536f * (x + 0.044715f*x*x*x);
  t = fminf(fmaxf(t, -15.f), 15.f);
  float e = __expf(2.f*t);
  float th = __fdividef(e - 1.f, e + 1.f);
  return 0.5f*x*(1.f + th);
}

// -------- twiddles: cos/sin(2*pi*k/32), f64-generated --------
__global__ void k_twiddle(float* __restrict__ twc, float* __restrict__ tws){
  int t = threadIdx.x;
  if(t < 32){
    double a = (double)t * 0.19634954084936207; // 2*pi/32
    twc[t] = (float)cos(a);
    tws[t] = (float)sin(a);
  }
}

// -------- f_in = x @ in_lift_w + b : [N_IN,64] --------
__global__ void k_lift_in(const float* __restrict__ x, const float* __restrict__ w,
                          const float* __restrict__ b, float* __restrict__ f){
  int i = blockIdx.x*256 + threadIdx.x;
  if(i >= N_IN*64) return;
  int p = i>>6, c = i&63;
  float v = b[c];
  v = fmaf(x[p*3+0], w[c],      v);
  v = fmaf(x[p*3+1], w[64+c],   v);
  v = fmaf(x[p*3+2], w[128+c],  v);
  f[i] = v;
}

// -------- sinusoidal embed (f64 angles) + partial matmul vs W0 rows --------
// out[p, c] = sum_i emb_p[i] * W[(roff+i)*COLS + c]  (+ bias[c])
template<int COLS, bool BIAS>
__global__ __launch_bounds__(256) void k_embed_partial(
    const float* __restrict__ coords, int npts,
    const float* __restrict__ W, int roff,
    const float* __restrict__ bias, float* __restrict__ outp)
{
  __shared__ float emb[96*8]; // [i][pl] : emb[i*8+pl]
  int p0 = blockIdx.x*8;
  int t  = threadIdx.x;
  for(int w = t; w < 384; w += 256){          // 8 points x 48 (d,freq) pairs
    int pl = w / 48, s = w - pl*48;
    int d = s >> 4, fi = s & 15;
    int p = p0 + pl;
    float cd = (p < npts) ? coords[(size_t)p*3 + d] : 0.f;
    double f = exp((double)fi * 0.5756462732485115); // ln(10000)/16
    double a = (double)cd * f;
    double sn, cs; sincos(a, &sn, &cs);
    emb[((d<<5)+fi)*8 + pl]      = (float)sn;
    emb[((d<<5)+16+fi)*8 + pl]   = (float)cs;
  }
  __syncthreads();
  for(int c = t; c < COLS; c += 256){
    float acc[8];
    float bb = BIAS ? bias[c] : 0.f;
    #pragma unroll
    for(int u=0;u<8;u++) acc[u] = bb;
    for(int i=0;i<96;i++){
      float wv = W[(size_t)(roff+i)*COLS + c];
      const float* ep = &emb[i*8];
      float4 e0 = *(const float4*)ep;
      float4 e1 = *(const float4*)(ep+4);
      acc[0]=fmaf(e0.x,wv,acc[0]); acc[1]=fmaf(e0.y,wv,acc[1]);
      acc[2]=fmaf(e0.z,wv,acc[2]); acc[3]=fmaf(e0.w,wv,acc[3]);
      acc[4]=fmaf(e1.x,wv,acc[4]); acc[5]=fmaf(e1.y,wv,acc[5]);
      acc[6]=fmaf(e1.z,wv,acc[6]); acc[7]=fmaf(e1.w,wv,acc[7]);
    }
    #pragma unroll
    for(int u=0;u<8;u++){
      int p = p0+u;
      if(p < npts) outp[(size_t)p*COLS + c] = acc[u];
    }
  }
}

// -------- input GNO: 4 queries/WG, 40 edges, MLP 80->80->80->64, mean --------
// hA/hB LDS layout: [col(80)][slot(48)], edge e -> slot (e/10)*12 + e%10
__global__ __launch_bounds__(128) void k_gno_in(
    const float* __restrict__ Ain, const float* __restrict__ Bin,
    const float* __restrict__ f_in, const int* __restrict__ iidx,
    const float* __restrict__ W1, const float* __restrict__ b1,
    const float* __restrict__ W2, const float* __restrict__ b2,
    const float* __restrict__ W3, const float* __restrict__ b3,
    float* __restrict__ in_p)
{
  __shared__ float hA[80][48];
  __shared__ float hB[80][48];
  __shared__ int   jj[40];
  int t = threadIdx.x;
  int q0 = blockIdx.x*4;
  if(t < 40) jj[t] = iidx[q0*10 + t];
  __syncthreads();

  // L0: gelu(Ain[j] + Bin[q]) -> hA
  for(int w = t; w < 3200; w += 128){
    int e = w / 80, c = w - e*80;
    int eg0 = e / 10;
    int sl = eg0*12 + (e - eg0*10);
    float v = Ain[(size_t)jj[e]*80 + c] + Bin[(size_t)(q0+eg0)*80 + c];
    hA[c][sl] = gelu_f(v);
  }
  __syncthreads();

  int c0 = (t % 20) * 4;
  int eg = t / 20;       // 0..3 for active threads (t<80)

#define GIN_LAYER(SRC, DST, WP, BP, OUTC, DOGELU)                              \
  if(t < 80 && c0 < (OUTC)){                                                   \
    float acc[4][10];                                                          \
    _Pragma("unroll") for(int u=0;u<4;u++)                                     \
      _Pragma("unroll") for(int k=0;k<10;k++) acc[u][k]=0.f;                   \
    for(int i=0;i<80;i++){                                                     \
      float4 wv = *(const float4*)&WP[i*(OUTC)+c0];                            \
      const float* hp = &SRC[i][eg*12];                                        \
      float4 h0 = *(const float4*)hp;                                          \
      float4 h1 = *(const float4*)(hp+4);                                      \
      float2 h2v = *(const float2*)(hp+8);                                     \
      float hv[10] = {h0.x,h0.y,h0.z,h0.w,h1.x,h1.y,h1.z,h1.w,h2v.x,h2v.y};    \
      _Pragma("unroll") for(int k=0;k<10;k++){                                 \
        acc[0][k]=fmaf(hv[k],wv.x,acc[0][k]);                                  \
        acc[1][k]=fmaf(hv[k],wv.y,acc[1][k]);                                  \
        acc[2][k]=fmaf(hv[k],wv.z,acc[2][k]);                                  \
        acc[3][k]=fmaf(hv[k],wv.w,acc[3][k]); }                                \
    }                                                                          \
    _Pragma("unroll") for(int u=0;u<4;u++){                                    \
      float bbv = BP[c0+u];                                                    \
      _Pragma("unroll") for(int k=0;k<10;k++){                                 \
        float v = acc[u][k] + bbv;                                             \
        DST[c0+u][eg*12+k] = (DOGELU) ? gelu_f(v) : v; } }                     \
  }                                                                            \
  __syncthreads();

  GIN_LAYER(hA, hB, W1, b1, 80, true)
  GIN_LAYER(hB, hA, W2, b2, 80, true)
  GIN_LAYER(hA, hB, W3, b3, 64, false)
#undef GIN_LAYER

  // reduce: mean over K with f modulation
  for(int w = t; w < 256; w += 128){
    int lq = w >> 6, oc = w & 63;
    float s = 0.f;
    #pragma unroll
    for(int k=0;k<10;k++){
      s = fmaf(hB[oc][lq*12+k], f_in[(size_t)jj[lq*10+k]*64 + oc], s);
    }
    in_p[(size_t)(q0+lq)*64 + oc] = s * 0.1f;
  }
}

// -------- row MLP 64->128(gelu)->64, optional gated epilogue --------
__global__ __launch_bounds__(256) void k_mlp_plain(const float* __restrict__ X,
    const float* __restrict__ W0, const float* __restrict__ b0,
    const float* __restrict__ W1, const float* __restrict__ b1,
    float* __restrict__ Y)
{
  __shared__ float xt[64*16];
  __shared__ float ht[128*16];
  int t = threadIdx.x, r0 = blockIdx.x*16;
  for(int w=t; w<1024; w+=256){ int r=w>>6, c=w&63; xt[c*16+r] = X[(size_t)(r0+r)*64+c]; }
  __syncthreads();
  {
    int hc = t & 127, rg = t >> 7;
    float acc[8]; float bb = b0[hc];
    #pragma unroll
    for(int u=0;u<8;u++) acc[u]=bb;
    for(int i=0;i<64;i++){
      float wv = W0[i*128+hc];
      const float* xp = &xt[i*16 + rg*8];
      float4 x0 = *(const float4*)xp; float4 x1 = *(const float4*)(xp+4);
      acc[0]=fmaf(x0.x,wv,acc[0]); acc[1]=fmaf(x0.y,wv,acc[1]);
      acc[2]=fmaf(x0.z,wv,acc[2]); acc[3]=fmaf(x0.w,wv,acc[3]);
      acc[4]=fmaf(x1.x,wv,acc[4]); acc[5]=fmaf(x1.y,wv,acc[5]);
      acc[6]=fmaf(x1.z,wv,acc[6]); acc[7]=fmaf(x1.w,wv,acc[7]);
    }
    #pragma unroll
    for(int u=0;u<8;u++) ht[hc*16 + rg*8 + u] = gelu_f(acc[u]);
  }
  __syncthreads();
  {
    int oc = t & 63, rg = t >> 6;
    float acc2[4]; float bb = b1[oc];
    #pragma unroll
    for(int u=0;u<4;u++) acc2[u]=bb;
    for(int i=0;i<128;i++){
      float wv = W1[i*64+oc];
      float4 h4 = *(const float4*)&ht[i*16 + rg*4];
      acc2[0]=fmaf(h4.x,wv,acc2[0]); acc2[1]=fmaf(h4.y,wv,acc2[1]);
      acc2[2]=fmaf(h4.z,wv,acc2[2]); acc2[3]=fmaf(h4.w,wv,acc2[3]);
    }
    #pragma unroll
    for(int u=0;u<4;u++) Y[(size_t)(r0+rg*4+u)*64 + oc] = acc2[u];
  }
}

__global__ __launch_bounds__(256) void k_mlp_gated(const float* __restrict__ X,
    const float* __restrict__ W0, const float* __restrict__ b0,
    const float* __restrict__ W1, const float* __restrict__ b1,
    const float* __restrict__ gwp, const float* __restrict__ gbp,
    float* __restrict__ Y)
{
  __shared__ float xt[64*16];
  __shared__ float ht[128*16];
  int t = threadIdx.x, r0 = blockIdx.x*16;
  for(int w=t; w<1024; w+=256){ int r=w>>6, c=w&63; xt[c*16+r] = X[(size_t)(r0+r)*64+c]; }
  __syncthreads();
  {
    int hc = t & 127, rg = t >> 7;
    float acc[8]; float bb = b0[hc];
    #pragma unroll
    for(int u=0;u<8;u++) acc[u]=bb;
    for(int i=0;i<64;i++){
      float wv = W0[i*128+hc];
      const float* xp = &xt[i*16 + rg*8];
      float4 x0 = *(const float4*)xp; float4 x1 = *(const float4*)(xp+4);
      acc[0]=fmaf(x0.x,wv,acc[0]); acc[1]=fmaf(x0.y,wv,acc[1]);
      acc[2]=fmaf(x0.z,wv,acc[2]); acc[3]=fmaf(x0.w,wv,acc[3]);
      acc[4]=fmaf(x1.x,wv,acc[4]); acc[5]=fmaf(x1.y,wv,acc[5]);
      acc[6]=fmaf(x1.z,wv,acc[6]); acc[7]=fmaf(x1.w,wv,acc[7]);
    }
    #pragma unroll
    for(int u=0;u<8;u++) ht[hc*16 + rg*8 + u] = gelu_f(acc[u]);
  }
  __syncthreads();
  {
    int oc = t & 63, rg = t >> 6;
    float acc2[4]; float bb = b1[oc];
    #pragma unroll
    for(int u=0;u<4;u++) acc2[u]=bb;
    for(int i=0;i<128;i++){
      float wv = W1[i*64+oc];
      float4 h4 = *(const float4*)&ht[i*16 + rg*4];
      acc2[0]=fmaf(h4.x,wv,acc2[0]); acc2[1]=fmaf(h4.y,wv,acc2[1]);
      acc2[2]=fmaf(h4.z,wv,acc2[2]); acc2[3]=fmaf(h4.w,wv,acc2[3]);
    }
    float gwv = gwp[oc], gbv = gbp[oc];
    #pragma unroll
    for(int u=0;u<4;u++){
      int r = rg*4+u;
      float a = xt[oc*16 + r];
      Y[(size_t)(r0+r)*64 + oc] = gelu_f(acc2[u] + fmaf(a, gwv, gbv));
    }
  }
}

// -------- truncated DFT stages --------
__global__ void k_fz_fwd(const float* __restrict__ h, const float* __restrict__ twc,
                         const float* __restrict__ tws, float* __restrict__ Fr, float* __restrict__ Fi){
  int idx = blockIdx.x*256 + threadIdx.x;   // [x 32][y 32][kz 8][c 64]
  int c = idx&63, kz=(idx>>6)&7, y=(idx>>9)&31, x=idx>>14;
  const float* hp = h + ((size_t)(x*32+y)*32)*64 + c;
  float re=0.f, im=0.f;
  for(int z=0; z<32; z++){
    float v = hp[(size_t)z*64];
    int k = (kz*z)&31;
    re = fmaf(v, twc[k], re);
    im = fmaf(-v, tws[k], im);
  }
  Fr[idx]=re; Fi[idx]=im;
}

__global__ void k_fy_fwd(const float* __restrict__ Ar, const float* __restrict__ Ai,
                         const float* __restrict__ twc, const float* __restrict__ tws,
                         float* __restrict__ Fr, float* __restrict__ Fi){
  int idx = blockIdx.x*256 + threadIdx.x;   // [x 32][my 16][kz 8][c 64]
  int c = idx&63, kz=(idx>>6)&7, my=(idx>>9)&15, x=idx>>13;
  int ky = my<8 ? my : my+16;
  const float* pr = Ar + ((size_t)(x*32)*8+kz)*64 + c;
  const float* pi = Ai + ((size_t)(x*32)*8+kz)*64 + c;
  float re=0.f, im=0.f;
  for(int y=0;y<32;y++){
    float a = pr[(size_t)y*512], b = pi[(size_t)y*512];
    int k = (ky*y)&31; float cs=twc[k], sn=tws[k];
    re += a*cs + b*sn;
    im += b*cs - a*sn;
  }
  Fr[idx]=re; Fi[idx]=im;
}

__global__ void k_fx_fwd(const float* __restrict__ Ar, const float* __restrict__ Ai,
                         const float* __restrict__ twc, const float* __restrict__ tws,
                         float* __restrict__ Fr, float* __restrict__ Fi){
  int idx = blockIdx.x*256 + threadIdx.x;   // [mx 16][my 16][kz 8][c 64]
  int c = idx&63, kz=(idx>>6)&7, my=(idx>>9)&15, mx=idx>>13;
  int kx = mx<8 ? mx : mx+16;
  const float* pr = Ar + ((size_t)my*8+kz)*64 + c;
  const float* pi = Ai + ((size_t)my*8+kz)*64 + c;
  float re=0.f, im=0.f;
  for(int x=0;x<32;x++){
    float a = pr[(size_t)x*8192], b = pi[(size_t)x*8192];
    int k = (kx*x)&31; float cs=twc[k], sn=tws[k];
    re += a*cs + b*sn;
    im += b*cs - a*sn;
  }
  Fr[idx]=re; Fi[idx]=im;
}

__global__ void k_smm(const float* __restrict__ Fr, const float* __restrict__ Fi,
                      const float* __restrict__ wlayer,
                      float* __restrict__ Gr, float* __restrict__ Gi){
  int mp = blockIdx.x;                      // (mx*16+my)*8+kz
  int kz = mp&7, my=(mp>>3)&15, mx=mp>>7;
  int corner = ((mx>=8)?2:0) | ((my>=8)?1:0);
  int kxp = mx&7, kyp = my&7;
  const float* wp = wlayer + (size_t)(((corner*8+kxp)*8+kyp)*8+kz)*8192; // 64*64*2
  __shared__ float fre[64], fim[64];
  int t = threadIdx.x;
  fre[t] = Fr[(size_t)mp*64+t];
  fim[t] = Fi[(size_t)mp*64+t];
  __syncthreads();
  float are=0.f, aim=0.f;
  for(int i=0;i<64;i++){
    float2 wv = *(const float2*)&wp[(size_t)(i*64+t)*2];
    float a = fre[i], b = fim[i];
    are += a*wv.x - b*wv.y;
    aim += a*wv.y + b*wv.x;
  }
  Gr[(size_t)mp*64+t] = are;
  Gi[(size_t)mp*64+t] = aim;
}

__global__ void k_fx_inv(const float* __restrict__ Ar, const float* __restrict__ Ai,
                         const float* __restrict__ twc, const float* __restrict__ tws,
                         float* __restrict__ Fr, float* __restrict__ Fi){
  int idx = blockIdx.x*256 + threadIdx.x;   // [x 32][my 16][kz 8][c 64]
  int c = idx&63, kz=(idx>>6)&7, my=(idx>>9)&15, x=idx>>13;
  float re=0.f, im=0.f;
  for(int mx=0;mx<16;mx++){
    int kx = mx<8 ? mx : mx+16;
    int k = (kx*x)&31; float cs=twc[k], sn=tws[k];
    float a = Ar[(size_t)((mx*16+my)*8+kz)*64+c];
    float b = Ai[(size_t)((mx*16+my)*8+kz)*64+c];
    re += a*cs - b*sn;
    im += a*sn + b*cs;
  }
  Fr[idx]=re; Fi[idx]=im;
}

__global__ void k_fy_inv(const float* __restrict__ Ar, const float* __restrict__ Ai,
                         const float* __restrict__ twc, const float* __restrict__ tws,
                         float* __restrict__ Fr, float* __restrict__ Fi){
  int idx = blockIdx.x*256 + threadIdx.x;   // [x 32][y 32][kz 8][c 64]
  int c = idx&63, kz=(idx>>6)&7, y=(idx>>9)&31, x=idx>>14;
  float re=0.f, im=0.f;
  for(int my=0;my<16;my++){
    int ky = my<8 ? my : my+16;
    int k = (ky*y)&31; float cs=twc[k], sn=tws[k];
    float a = Ar[(size_t)((x*16+my)*8+kz)*64+c];
    float b = Ai[(size_t)((x*16+my)*8+kz)*64+c];
    re += a*cs - b*sn;
    im += a*sn + b*cs;
  }
  Fr[idx]=re; Fi[idx]=im;
}

// z real-inverse (pocketfft c2r convention: Im of bin0 dropped) + skip + gelu
__global__ void k_fz_inv_skip(const float* __restrict__ G2re, const float* __restrict__ G2im,
    const float* __restrict__ h, const float* __restrict__ twc, const float* __restrict__ tws,
    const float* __restrict__ sw, float* __restrict__ a_out)
{
  __shared__ float hrow[4][64];
  int t = threadIdx.x; int c = t&63; int pl = t>>6;
  int p = blockIdx.x*4 + pl;
  int z = p & 31; int xy = p >> 5;
  hrow[pl][c] = h[(size_t)p*64 + c];
  __syncthreads();
  const float* gr = G2re + (size_t)(xy*8)*64 + c;
  const float* gi = G2im + (size_t)(xy*8)*64 + c;
  float acc = gr[0];
  #pragma unroll
  for(int kz=1;kz<8;kz++){
    int k = (kz*z)&31;
    acc += 2.f*(gr[(size_t)kz*64]*twc[k] - gi[(size_t)kz*64]*tws[k]);
  }
  float vfno = acc * (1.f/32768.f);
  float vskip = 0.f;
  for(int i=0;i<64;i++) vskip = fmaf(hrow[pl][i], sw[i*64+c], vskip);
  a_out[(size_t)p*64+c] = gelu_f(vfno + vskip);
}

// -------- output GNO GEMM1: H2 = gelu(gelu(Aout[j]+Bout[q]) @ W1 + b1) --------
__global__ __launch_bounds__(256) void k_ogemm1(const float* __restrict__ Aout,
    const float* __restrict__ Bout, const int* __restrict__ oidx,
    const float* __restrict__ W1, const float* __restrict__ bias1,
    int e0, int eEnd, float* __restrict__ H2)
{
  __shared__ float aT[16][64];
  __shared__ float bT[16][256];
  __shared__ int js[64]; __shared__ int qs[64];
  int t = threadIdx.x;
  int et0 = e0 + blockIdx.x*64;
  if(t<64){
    int e = et0 + t;
    int ec = e < eEnd ? e : eEnd-1;
    js[t] = oidx[ec]; qs[t] = ec/10;
  }
  __syncthreads();
  int eload = t>>2, i0 = (t&3)*4;
  const float* ap = Aout + (size_t)js[eload]*512 + i0;
  const float* bp = Bout + (size_t)qs[eload]*512 + i0;
  int c4b = (t&63)*4, irb = t>>6;
  int rg = t>>5, c4 = (t&31)*4;
  float acc[8][8] = {};
  for(int kk=0; kk<512; kk+=16){
    float4 av = *(const float4*)(ap+kk);
    float4 bv = *(const float4*)(bp+kk);
    aT[i0+0][eload] = gelu_f(av.x+bv.x);
    aT[i0+1][eload] = gelu_f(av.y+bv.y);
    aT[i0+2][eload] = gelu_f(av.z+bv.z);
    aT[i0+3][eload] = gelu_f(av.w+bv.w);
    #pragma unroll
    for(int u=0;u<4;u++){
      int i = irb + u*4;
      *(float4*)&bT[i][c4b] = *(const float4*)&W1[(size_t)(kk+i)*256 + c4b];
    }
    __syncthreads();
    #pragma unroll
    for(int k=0;k<16;k++){
      const float* arow = aT[k]; const float* brow = bT[k];
      float4 a0 = *(const float4*)(arow + rg*8);
      float4 a1 = *(const float4*)(arow + rg*8 + 4);
      float4 b0 = *(const float4*)(brow + c4);
      float4 b1v= *(const float4*)(brow + c4 + 128);
      float avr[8] = {a0.x,a0.y,a0.z,a0.w,a1.x,a1.y,a1.z,a1.w};
      float bvr[8] = {b0.x,b0.y,b0.z,b0.w,b1v.x,b1v.y,b1v.z,b1v.w};
      #pragma unroll
      for(int ur=0;ur<8;ur++)
        #pragma unroll
        for(int uc=0;uc<8;uc++)
          acc[ur][uc] = fmaf(avr[ur], bvr[uc], acc[ur][uc]);
    }
    __syncthreads();
  }
  float bb[8];
  #pragma unroll
  for(int u=0;u<4;u++){ bb[u]=bias1[c4+u]; bb[4+u]=bias1[c4+128+u]; }
  #pragma unroll
  for(int ur=0;ur<8;ur++){
    int e = et0 + rg*8 + ur;
    if(e < eEnd){
      float* hp = H2 + (size_t)(e - e0)*256;
      float4 v0, v1;
      v0.x=gelu_f(acc[ur][0]+bb[0]); v0.y=gelu_f(acc[ur][1]+bb[1]);
      v0.z=gelu_f(acc[ur][2]+bb[2]); v0.w=gelu_f(acc[ur][3]+bb[3]);
      v1.x=gelu_f(acc[ur][4]+bb[4]); v1.y=gelu_f(acc[ur][5]+bb[5]);
      v1.z=gelu_f(acc[ur][6]+bb[6]); v1.w=gelu_f(acc[ur][7]+bb[7]);
      *(float4*)(hp + c4)       = v0;
      *(float4*)(hp + c4 + 128) = v1;
    }
  }
}

// -------- output GNO GEMM2: kv = H2@W2 + b2; msg += kv * xlat[j] (atomic) --------
__global__ __launch_bounds__(256) void k_ogemm2(const float* __restrict__ H2,
    const float* __restrict__ W2, const float* __restrict__ bias2,
    const float* __restrict__ xlat, const int* __restrict__ oidx,
    int e0, int eEnd, float* __restrict__ outev)
{
  __shared__ float aT[16][64];
  __shared__ float bT[16][64];
  __shared__ int js[64]; __shared__ int qs[64];
  int t = threadIdx.x;
  int et0 = e0 + blockIdx.x*64;
  if(t<64){ int e=et0+t; int ec = e<eEnd ? e : eEnd-1; js[t]=oidx[ec]; qs[t]=ec/10; }
  __syncthreads();
  int eload = t>>2, i0=(t&3)*4;
  bool rv = (et0 + eload) < eEnd;
  const float* hp = H2 + (size_t)(et0 - e0 + (rv ? eload : 0))*256 + i0;
  int wr = t>>4, wc4 = (t&15)*4;
  int rg = t>>4, c4 = (t&15)*4;
  float acc[4][4] = {};
  for(int kk=0; kk<256; kk+=16){
    float4 hv = *(const float4*)(hp+kk);
    aT[i0+0][eload]=hv.x; aT[i0+1][eload]=hv.y; aT[i0+2][eload]=hv.z; aT[i0+3][eload]=hv.w;
    *(float4*)&bT[wr][wc4] = *(const float4*)&W2[(size_t)(kk+wr)*64 + wc4];
    __syncthreads();
    #pragma unroll
    for(int k=0;k<16;k++){
      float4 a = *(const float4*)(aT[k] + rg*4);
      float4 b = *(const float4*)(bT[k] + c4);
      float avr[4]={a.x,a.y,a.z,a.w}, bvr[4]={b.x,b.y,b.z,b.w};
      #pragma unroll
      for(int ur=0;ur<4;ur++)
        #pragma unroll
        for(int uc=0;uc<4;uc++)
          acc[ur][uc] = fmaf(avr[ur], bvr[uc], acc[ur][uc]);
    }
    __syncthreads();
  }
  #pragma unroll
  for(int ur=0;ur<4;ur++){
    int row = rg*4+ur; int e = et0+row;
    if(e < eEnd){
      int j = js[row], q = qs[row];
      #pragma unroll
      for(int uc=0;uc<4;uc++){
        int c = c4+uc;
        float v = (acc[ur][uc] + bias2[c]) * xlat[(size_t)j*64 + c];
        atomicAdd(&outev[(size_t)q*64 + c], v);
      }
    }
  }
}

// -------- projection: out[q] = gelu(msg@pw0+pb0)@pw1 + pb1 --------
__global__ __launch_bounds__(256) void k_proj(const float* __restrict__ outev,
    const float* __restrict__ pw0, const float* __restrict__ pb0,
    const float* __restrict__ pw1, const float* __restrict__ pb1,
    float* __restrict__ outp)
{
  __shared__ float msg[8][64];
  __shared__ float red[8][4];
  int t = threadIdx.x; int q0 = blockIdx.x*8;
  for(int w=t; w<512; w+=256){
    int qq=w>>6, o=w&63; int q=q0+qq;
    msg[qq][o] = (q<N_OUT) ? outev[(size_t)q*64+o] : 0.f;
  }
  __syncthreads();
  float p[8]; float bb = pb0[t];
  #pragma unroll
  for(int qq=0;qq<8;qq++) p[qq]=bb;
  for(int o=0;o<64;o++){
    float wv = pw0[o*256+t];
    #pragma unroll
    for(int qq=0;qq<8;qq++) p[qq] = fmaf(msg[qq][o], wv, p[qq]);
  }
  float w1v = pw1[t];
  int lane = t & 63, wid = t >> 6;
  #pragma unroll
  for(int qq=0;qq<8;qq++){
    float v = gelu_f(p[qq]) * w1v;
    for(int d=32; d>=1; d>>=1) v += __shfl_down(v, d, 64);
    if(lane==0) red[qq][wid]=v;
  }
  __syncthreads();
  if(t<8){
    int q = q0+t;
    if(q<N_OUT) outp[q] = red[t][0]+red[t][1]+red[t][2]+red[t][3] + pb1[0];
  }
}

// ==================== host ====================
extern "C" void kernel_launch(void* const* d_in, const int* in_sizes, int n_in,
                              void* d_out, int out_size, void* d_ws, size_t ws_size,
                              hipStream_t stream)
{
  (void)in_sizes; (void)n_in; (void)out_size;
  const float* geom = (const float*)d_in[0];
  const float* latq = (const float*)d_in[1];
  const float* outq = (const float*)d_in[2];
  const float* xin  = (const float*)d_in[3];
  const float* ilw  = (const float*)d_in[4];
  const float* ilb  = (const float*)d_in[5];
  const float* ikw0 = (const float*)d_in[6];
  const float* ikb0 = (const float*)d_in[7];
  const float* ikw1 = (const float*)d_in[8];
  const float* ikb1 = (const float*)d_in[9];
  const float* ikw2 = (const float*)d_in[10];
  const float* ikb2 = (const float*)d_in[11];
  const float* ikw3 = (const float*)d_in[12];
  const float* ikb3 = (const float*)d_in[13];
  const float* lw0  = (const float*)d_in[14];
  const float* lb0  = (const float*)d_in[15];
  const float* lw1  = (const float*)d_in[16];
  const float* lb1  = (const float*)d_in[17];
  const float* specw= (const float*)d_in[18];
  const float* skw  = (const float*)d_in[19];
  const float* gw   = (const float*)d_in[20];
  const float* gb   = (const float*)d_in[21];
  const float* cw0  = (const float*)d_in[22];
  const float* cb0  = (const float*)d_in[23];
  const float* cw1  = (const float*)d_in[24];
  const float* cb1  = (const float*)d_in[25];
  const float* okw0 = (const float*)d_in[26];
  const float* okb0 = (const float*)d_in[27];
  const float* okw1 = (const float*)d_in[28];
  const float* okb1 = (const float*)d_in[29];
  const float* okw2 = (const float*)d_in[30];
  const float* okb2 = (const float*)d_in[31];
  const float* pw0  = (const float*)d_in[32];
  const float* pb0  = (const float*)d_in[33];
  const float* pw1  = (const float*)d_in[34];
  const float* pb1  = (const float*)d_in[35];
  const int* iidx = (const int*)d_in[36];
  const int* oidx = (const int*)d_in[37];
  float* outp = (float*)d_out;
  float* ws = (float*)d_ws;

  size_t off = 0;
  float* F_IN = ws + off; off += (size_t)N_IN*64;
  float* AIN  = ws + off; off += (size_t)N_IN*80;
  float* BIN_ = ws + off; off += (size_t)N_LQ*80;
  float* AOUT = ws + off; off += (size_t)N_LQ*512;
  float* BOUT = ws + off; off += (size_t)N_OUT*512;
  float* HBUF = ws + off; off += (size_t)N_LQ*64;
  float* ABUF = ws + off; off += (size_t)N_LQ*64;
  float* FZr = ws+off; off+=524288; float* FZi = ws+off; off+=524288;
  float* FYr = ws+off; off+=262144; float* FYi = ws+off; off+=262144;
  float* FXr = ws+off; off+=131072; float* FXi = ws+off; off+=131072;
  float* GMr = ws+off; off+=131072; float* GMi = ws+off; off+=131072;
  float* G1r = ws+off; off+=262144; float* G1i = ws+off; off+=262144;
  float* G2r = ws+off; off+=524288; float* G2i = ws+off; off+=524288;
  float* OUTEV = ws+off; off += (size_t)N_OUT*64;
  float* TWC = ws+off; off+=32; float* TWS = ws+off; off+=32;
  float* H2C = ws+off;
  size_t availF = (ws_size/4 > off) ? (ws_size/4 - off) : 0;
  int chunkq = 6000;
  if((size_t)chunkq*2560 > availF) chunkq = (int)(availF/2560);
  if(chunkq < 250) chunkq = 250;

  k_twiddle<<<1, 64, 0, stream>>>(TWC, TWS);
  k_lift_in<<<(N_IN*64)/256, 256, 0, stream>>>(xin, ilw, ilb, F_IN);
  k_embed_partial<80,false><<<N_IN/8, 256, 0, stream>>>(geom, N_IN, ikw0, 0, (const float*)nullptr, AIN);
  k_embed_partial<80,true ><<<N_LQ/8, 256, 0, stream>>>(latq, N_LQ, ikw0, 96, ikb0, BIN_);
  k_embed_partial<512,false><<<N_LQ/8, 256, 0, stream>>>(latq, N_LQ, okw0, 0, (const float*)nullptr, AOUT);
  k_embed_partial<512,true ><<<N_OUT/8, 256, 0, stream>>>(outq, N_OUT, okw0, 96, okb0, BOUT);
  k_gno_in<<<N_LQ/4, 128, 0, stream>>>(AIN, BIN_, F_IN, iidx, ikw1, ikb1, ikw2, ikb2, ikw3, ikb3, HBUF);
  k_mlp_plain<<<N_LQ/16, 256, 0, stream>>>(HBUF, lw0, lb0, lw1, lb1, HBUF);

  for(int l=0;l<4;l++){
    k_fz_fwd<<<2048,256,0,stream>>>(HBUF, TWC, TWS, FZr, FZi);
    k_fy_fwd<<<1024,256,0,stream>>>(FZr, FZi, TWC, TWS, FYr, FYi);
    k_fx_fwd<<<512,256,0,stream>>>(FYr, FYi, TWC, TWS, FXr, FXi);
    k_smm<<<2048,64,0,stream>>>(FXr, FXi, specw + (size_t)l*16777216, GMr, GMi);
    k_fx_inv<<<1024,256,0,stream>>>(GMr, GMi, TWC, TWS, G1r, G1i);
    k_fy_inv<<<2048,256,0,stream>>>(G1r, G1i, TWC, TWS, G2r, G2i);
    k_fz_inv_skip<<<8192,256,0,stream>>>(G2r, G2i, HBUF, TWC, TWS, skw + (size_t)l*4096, ABUF);
    k_mlp_gated<<<N_LQ/16,256,0,stream>>>(ABUF, cw0 + (size_t)l*8192, cb0 + l*128,
                                          cw1 + (size_t)l*8192, cb1 + l*64,
                                          gw + l*64, gb + l*64, HBUF);
  }

  hipMemsetAsync(OUTEV, 0, (size_t)N_OUT*64*sizeof(float), stream);
  for(int q0 = 0; q0 < N_OUT; q0 += chunkq){
    int q1 = (q0+chunkq < N_OUT) ? q0+chunkq : N_OUT;
    int e0 = q0*KNB, eE = q1*KNB;
    int nt = (eE - e0 + 63)/64;
    k_ogemm1<<<nt,256,0,stream>>>(AOUT, BOUT, oidx, okw1, okb1, e0, eE, H2C);
    k_ogemm2<<<nt,256,0,stream>>>(H2C, okw2, okb2, HBUF, oidx, e0, eE, OUTEV);
  }
  k_proj<<<(N_OUT+7)/8, 256, 0, stream>>>(OUTEV, pw0, pb0, pw1, pb1, outp);
}

// Round 3
// 1957.214 us; speedup vs baseline: 1.4597x; 1.4597x over previous
//
#include <hip/hip_runtime.h>
#include <math.h>

// GINO forward. f32 everywhere except GNO MLP GEMMs, which use split-f16
// MFMA (hi + lo*2^-11, 3 MFMAs per product pair -> ~2^-22 relative error).
#define N_IN   100000
#define N_LQ   32768
#define N_OUT  30000
#define KNB    10

typedef _Float16 h8 __attribute__((ext_vector_type(8)));
typedef _Float16 h4 __attribute__((ext_vector_type(4)));
typedef float    v4f __attribute__((ext_vector_type(4)));

__device__ __forceinline__ float gelu_f(float x){
  float t = 0.79788456080286536f * (x + 0.044715f*x*x*x);
  t = fminf(fmaxf(t, -15.f), 15.f);
  float e = __expf(2.f*t);
  float th = __fdividef(e - 1.f, e + 1.f);
  return 0.5f*x*(1.f + th);
}

// -------- twiddles --------
__global__ void k_twiddle(float* __restrict__ twc, float* __restrict__ tws){
  int t = threadIdx.x;
  if(t < 32){
    double a = (double)t * 0.19634954084936207; // 2*pi/32
    twc[t] = (float)cos(a);
    tws[t] = (float)sin(a);
  }
}

// -------- weight split/transpose for MFMA kernels --------
// OW1: okw1 [512][256] -> W1T[n(256)][k(512)] hi/lo
// OW2: okw2 [256][64]  -> W2T[n(64)][k(256)]  hi/lo
// I1/I2: ikw1/2 [80][80] -> [n(80)][k(80)] ; I3: ikw3 [80][64] -> [n(64)][k(80)]
__global__ void k_prep(const float* __restrict__ okw1, const float* __restrict__ okw2,
                       const float* __restrict__ ikw1, const float* __restrict__ ikw2,
                       const float* __restrict__ ikw3,
                       _Float16* W1h, _Float16* W1l, _Float16* W2h, _Float16* W2l,
                       _Float16* I1h, _Float16* I1l, _Float16* I2h, _Float16* I2l,
                       _Float16* I3h, _Float16* I3l)
{
  int idx = blockIdx.x*256 + threadIdx.x;
  if(idx < 512*256){
    int k = idx>>8, n = idx&255;
    float v = okw1[idx];
    _Float16 hi = (_Float16)v;
    W1h[n*512+k] = hi; W1l[n*512+k] = (_Float16)((v-(float)hi)*2048.f);
  }
  if(idx < 256*64){
    int k = idx>>6, n = idx&63;
    float v = okw2[idx];
    _Float16 hi = (_Float16)v;
    W2h[n*256+k] = hi; W2l[n*256+k] = (_Float16)((v-(float)hi)*2048.f);
  }
  if(idx < 6400){
    int n = idx/80, k = idx - n*80;
    float v = ikw1[k*80+n];
    _Float16 hi = (_Float16)v;
    I1h[n*80+k] = hi; I1l[n*80+k] = (_Float16)((v-(float)hi)*2048.f);
    float v2 = ikw2[k*80+n];
    _Float16 hi2 = (_Float16)v2;
    I2h[n*80+k] = hi2; I2l[n*80+k] = (_Float16)((v2-(float)hi2)*2048.f);
  }
  if(idx < 5120){
    int n = idx/80, k = idx - n*80;
    float v = ikw3[k*64+n];
    _Float16 hi = (_Float16)v;
    I3h[n*80+k] = hi; I3l[n*80+k] = (_Float16)((v-(float)hi)*2048.f);
  }
}

// -------- f_in = x @ in_lift_w + b --------
__global__ void k_lift_in(const float* __restrict__ x, const float* __restrict__ w,
                          const float* __restrict__ b, float* __restrict__ f){
  int i = blockIdx.x*256 + threadIdx.x;
  if(i >= N_IN*64) return;
  int p = i>>6, c = i&63;
  float v = b[c];
  v = fmaf(x[p*3+0], w[c],      v);
  v = fmaf(x[p*3+1], w[64+c],   v);
  v = fmaf(x[p*3+2], w[128+c],  v);
  f[i] = v;
}

// -------- sinusoidal embed (f64 angles) + partial matmul vs W0 rows --------
template<int COLS, bool BIAS>
__global__ __launch_bounds__(256) void k_embed_partial(
    const float* __restrict__ coords, int npts,
    const float* __restrict__ W, int roff,
    const float* __restrict__ bias, float* __restrict__ outp)
{
  __shared__ float emb[96*8];
  int p0 = blockIdx.x*8;
  int t  = threadIdx.x;
  for(int w = t; w < 384; w += 256){
    int pl = w / 48, s = w - pl*48;
    int d = s >> 4, fi = s & 15;
    int p = p0 + pl;
    float cd = (p < npts) ? coords[(size_t)p*3 + d] : 0.f;
    double f = exp((double)fi * 0.5756462732485115); // ln(10000)/16
    double a = (double)cd * f;
    double sn, cs; sincos(a, &sn, &cs);
    emb[((d<<5)+fi)*8 + pl]      = (float)sn;
    emb[((d<<5)+16+fi)*8 + pl]   = (float)cs;
  }
  __syncthreads();
  for(int c = t; c < COLS; c += 256){
    float acc[8];
    float bb = BIAS ? bias[c] : 0.f;
    #pragma unroll
    for(int u=0;u<8;u++) acc[u] = bb;
    for(int i=0;i<96;i++){
      float wv = W[(size_t)(roff+i)*COLS + c];
      const float* ep = &emb[i*8];
      float4 e0 = *(const float4*)ep;
      float4 e1 = *(const float4*)(ep+4);
      acc[0]=fmaf(e0.x,wv,acc[0]); acc[1]=fmaf(e0.y,wv,acc[1]);
      acc[2]=fmaf(e0.z,wv,acc[2]); acc[3]=fmaf(e0.w,wv,acc[3]);
      acc[4]=fmaf(e1.x,wv,acc[4]); acc[5]=fmaf(e1.y,wv,acc[5]);
      acc[6]=fmaf(e1.z,wv,acc[6]); acc[7]=fmaf(e1.w,wv,acc[7]);
    }
    #pragma unroll
    for(int u=0;u<8;u++){
      int p = p0+u;
      if(p < npts) outp[(size_t)p*COLS + c] = acc[u];
    }
  }
}

// ==================== input GNO via split-f16 MFMA ====================
// 64 edges/block, MLP 80->80->80->64 (K chunks 32,32,16), mean-reduce via atomics.
#define GI_HAHI 0
#define GI_HALO 5632
#define GI_WHI  11264
#define GI_WLO  14464
__global__ __launch_bounds__(256,2) void k_gino(
    const float* __restrict__ Ain, const float* __restrict__ Bin,
    const float* __restrict__ f_in, const int* __restrict__ iidx,
    const _Float16* __restrict__ I1h, const _Float16* __restrict__ I1l, const float* __restrict__ b1,
    const _Float16* __restrict__ I2h, const _Float16* __restrict__ I2l, const float* __restrict__ b2,
    const _Float16* __restrict__ I3h, const _Float16* __restrict__ I3l, const float* __restrict__ b3,
    float* __restrict__ in_p)
{
  __shared__ _Float16 SG[17664];
  __shared__ int js[64]; __shared__ int qs[64];
  int t = threadIdx.x;
  int wid = t>>6, lane = t&63, quad = lane>>4, lm = lane&15;
  int et0 = blockIdx.x*64;
  if(t<64){ js[t] = iidx[et0+t]; qs[t] = (et0+t)/KNB; }
  __syncthreads();

  // L0 staging: gelu(Ain[j] + Bin[q]) split -> hA
  {
    int e = t>>2, k4 = t&3;
    size_t ja = (size_t)js[e]*80, qa = (size_t)qs[e]*80;
    #pragma unroll
    for(int u=0;u<3;u++){
      int kl = k4*8 + u*32;
      if(kl < 80){
        float4 a0 = *(const float4*)(Ain + ja + kl);
        float4 a1 = *(const float4*)(Ain + ja + kl + 4);
        float4 c0 = *(const float4*)(Bin + qa + kl);
        float4 c1 = *(const float4*)(Bin + qa + kl + 4);
        float vv[8] = {a0.x+c0.x, a0.y+c0.y, a0.z+c0.z, a0.w+c0.w,
                       a1.x+c1.x, a1.y+c1.y, a1.z+c1.z, a1.w+c1.w};
        h8 hh, ll;
        #pragma unroll
        for(int q8=0;q8<8;q8++){
          float g = gelu_f(vv[q8]);
          _Float16 hi = (_Float16)g;
          hh[q8] = hi; ll[q8] = (_Float16)((g-(float)hi)*2048.f);
        }
        *(h8*)&SG[GI_HAHI + e*88 + kl] = hh;
        *(h8*)&SG[GI_HALO + e*88 + kl] = ll;
      }
    }
  }

  const float inv = 4.8828125e-4f;
  const _Float16* whp[3] = {I1h, I2h, I3h};
  const _Float16* wlp[3] = {I1l, I2l, I3l};
  const float*    bsp[3] = {b1, b2, b3};
  v4f aH[5], aL[5];

  for(int l=0;l<3;l++){
    int NT = (l==2)?4:5;
    const _Float16* wh = whp[l];
    const _Float16* wl = wlp[l];
    #pragma unroll
    for(int n=0;n<5;n++){ aH[n] = (v4f)(0.f); aL[n] = (v4f)(0.f); }
    for(int c=0;c<3;c++){
      int kb = c*32;
      int per = (c==2)?2:4;
      int units = NT*16*per;
      __syncthreads();
      for(int u=t; u<units; u+=256){
        int n = u/per, kh = (u - n*per)*8;
        float4 rh = *(const float4*)(wh + n*80 + kb + kh);
        float4 rl = *(const float4*)(wl + n*80 + kb + kh);
        *(float4*)&SG[GI_WHI + n*40 + kh] = rh;
        *(float4*)&SG[GI_WLO + n*40 + kh] = rl;
      }
      __syncthreads();
      int arow = (wid*16+lm)*88;
      if(c<2){
        h8 ah = *(const h8*)&SG[GI_HAHI + arow + kb + quad*8];
        h8 al = *(const h8*)&SG[GI_HALO + arow + kb + quad*8];
        for(int n=0;n<NT;n++){
          int brow = (n*16+lm)*40;
          h8 bh = *(const h8*)&SG[GI_WHI + brow + quad*8];
          h8 bl = *(const h8*)&SG[GI_WLO + brow + quad*8];
          aH[n] = __builtin_amdgcn_mfma_f32_16x16x32_f16(ah, bh, aH[n], 0,0,0);
          aL[n] = __builtin_amdgcn_mfma_f32_16x16x32_f16(ah, bl, aL[n], 0,0,0);
          aL[n] = __builtin_amdgcn_mfma_f32_16x16x32_f16(al, bh, aL[n], 0,0,0);
        }
      } else {
        h4 ah = *(const h4*)&SG[GI_HAHI + arow + 64 + quad*4];
        h4 al = *(const h4*)&SG[GI_HALO + arow + 64 + quad*4];
        for(int n=0;n<NT;n++){
          int brow = (n*16+lm)*40;
          h4 bh = *(const h4*)&SG[GI_WHI + brow + quad*4];
          h4 bl = *(const h4*)&SG[GI_WLO + brow + quad*4];
          aH[n] = __builtin_amdgcn_mfma_f32_16x16x16f16(ah, bh, aH[n], 0,0,0);
          aL[n] = __builtin_amdgcn_mfma_f32_16x16x16f16(ah, bl, aL[n], 0,0,0);
          aL[n] = __builtin_amdgcn_mfma_f32_16x16x16f16(al, bh, aL[n], 0,0,0);
        }
      }
    }
    if(l<2){
      for(int n=0;n<NT;n++){
        float bb = bsp[l][n*16+lm];
        #pragma unroll
        for(int reg=0;reg<4;reg++){
          int e = wid*16 + quad*4 + reg;
          float v = aH[n][reg] + aL[n][reg]*inv + bb;
          v = gelu_f(v);
          _Float16 hi = (_Float16)v;
          SG[GI_HAHI + e*88 + n*16+lm] = hi;
          SG[GI_HALO + e*88 + n*16+lm] = (_Float16)((v-(float)hi)*2048.f);
        }
      }
    } else {
      for(int n=0;n<NT;n++){
        int col = n*16+lm;
        float bb = bsp[2][col];
        #pragma unroll
        for(int reg=0;reg<4;reg++){
          int e = wid*16 + quad*4 + reg;
          float v = aH[n][reg] + aL[n][reg]*inv + bb;
          v *= f_in[(size_t)js[e]*64 + col] * 0.1f;
          atomicAdd(&in_p[(size_t)qs[e]*64 + col], v);
        }
      }
    }
  }
}

// ==================== output GNO via split-f16 MFMA (fused) ====================
#define OG_AHI  0
#define OG_ALO  2560
#define OG_BHI  5120
#define OG_BLO  15360
#define OG_W2HI 0
#define OG_W2LO 2560
#define OG_H1HI 5120
#define OG_H1LO 7680
__global__ __launch_bounds__(256,2) void k_ogno(
    const float* __restrict__ Aout, const float* __restrict__ Bout,
    const int* __restrict__ oidx,
    const _Float16* __restrict__ W1h, const _Float16* __restrict__ W1l,
    const float* __restrict__ b1,
    const _Float16* __restrict__ W2h, const _Float16* __restrict__ W2l,
    const float* __restrict__ b2,
    const float* __restrict__ xlat, float* __restrict__ outev, int eEnd)
{
  __shared__ _Float16 SH[25600];
  __shared__ int js[64]; __shared__ int qs[64];
  int t = threadIdx.x;
  int wid = t>>6, lane = t&63, quad = lane>>4, lm = lane&15;
  int et0 = blockIdx.x*64;
  if(t<64){
    int ec = et0+t; if(ec >= eEnd) ec = eEnd-1;
    js[t] = oidx[ec]; qs[t] = ec/KNB;
  }
  __syncthreads();

  v4f accH[4][4], accL[4][4];
  #pragma unroll
  for(int m=0;m<4;m++)
    #pragma unroll
    for(int n=0;n<4;n++){ accH[m][n] = (v4f)(0.f); accL[m][n] = (v4f)(0.f); }

  int se = t>>2, skl = (t&3)*8;
  size_t sja = (size_t)js[se]*512 + skl;
  size_t sqa = (size_t)qs[se]*512 + skl;

  for(int kk=0; kk<512; kk+=32){
    {
      const float* pa = Aout + sja + kk;
      const float* pb = Bout + sqa + kk;
      float4 a0 = *(const float4*)pa;
      float4 a1 = *(const float4*)(pa+4);
      float4 c0 = *(const float4*)pb;
      float4 c1 = *(const float4*)(pb+4);
      float vv[8] = {a0.x+c0.x, a0.y+c0.y, a0.z+c0.z, a0.w+c0.w,
                     a1.x+c1.x, a1.y+c1.y, a1.z+c1.z, a1.w+c1.w};
      h8 hh, ll;
      #pragma unroll
      for(int q8=0;q8<8;q8++){
        float g = gelu_f(vv[q8]);
        _Float16 hi = (_Float16)g;
        hh[q8] = hi; ll[q8] = (_Float16)((g-(float)hi)*2048.f);
      }
      *(h8*)&SH[OG_AHI + se*40 + skl] = hh;
      *(h8*)&SH[OG_ALO + se*40 + skl] = ll;
    }
    {
      const float4* ph = (const float4*)(W1h + (size_t)t*512 + kk);
      const float4* pl = (const float4*)(W1l + (size_t)t*512 + kk);
      float4 r0=ph[0], r1=ph[1], r2=ph[2], r3=ph[3];
      *(float4*)&SH[OG_BHI + t*40 +  0] = r0;
      *(float4*)&SH[OG_BHI + t*40 +  8] = r1;
      *(float4*)&SH[OG_BHI + t*40 + 16] = r2;
      *(float4*)&SH[OG_BHI + t*40 + 24] = r3;
      r0=pl[0]; r1=pl[1]; r2=pl[2]; r3=pl[3];
      *(float4*)&SH[OG_BLO + t*40 +  0] = r0;
      *(float4*)&SH[OG_BLO + t*40 +  8] = r1;
      *(float4*)&SH[OG_BLO + t*40 + 16] = r2;
      *(float4*)&SH[OG_BLO + t*40 + 24] = r3;
    }
    __syncthreads();
    h8 ah[4], al[4];
    #pragma unroll
    for(int m=0;m<4;m++){
      ah[m] = *(const h8*)&SH[OG_AHI + (m*16+lm)*40 + quad*8];
      al[m] = *(const h8*)&SH[OG_ALO + (m*16+lm)*40 + quad*8];
    }
    for(int n=0;n<4;n++){
      int nr = ((wid*4+n)*16+lm)*40 + quad*8;
      h8 bh = *(const h8*)&SH[OG_BHI + nr];
      h8 bl = *(const h8*)&SH[OG_BLO + nr];
      #pragma unroll
      for(int m=0;m<4;m++){
        accH[m][n] = __builtin_amdgcn_mfma_f32_16x16x32_f16(ah[m], bh, accH[m][n], 0,0,0);
        accL[m][n] = __builtin_amdgcn_mfma_f32_16x16x32_f16(ah[m], bl, accL[m][n], 0,0,0);
        accL[m][n] = __builtin_amdgcn_mfma_f32_16x16x32_f16(al[m], bh, accL[m][n], 0,0,0);
      }
    }
    __syncthreads();
  }

  // GEMM2
  const float inv = 4.8828125e-4f;
  v4f acc2H[4], acc2L[4];
  #pragma unroll
  for(int m=0;m<4;m++){ acc2H[m] = (v4f)(0.f); acc2L[m] = (v4f)(0.f); }

  for(int w2=0; w2<4; ++w2){
    for(int s=0; s<2; ++s){
      int ksub = w2*64 + s*32;
      {
        int n2 = t&63, kh = (t>>6)*8;
        float4 rh = *(const float4*)(W2h + (size_t)n2*256 + ksub + kh);
        float4 rl = *(const float4*)(W2l + (size_t)n2*256 + ksub + kh);
        *(float4*)&SH[OG_W2HI + n2*40 + kh] = rh;
        *(float4*)&SH[OG_W2LO + n2*40 + kh] = rl;
      }
      if(wid == w2){
        #pragma unroll
        for(int tt=0;tt<2;tt++){
          int n = 2*s+tt;
          float bb = b1[(w2*4+n)*16 + lm];
          #pragma unroll
          for(int m=0;m<4;m++){
            #pragma unroll
            for(int reg=0;reg<4;reg++){
              int e = m*16 + quad*4 + reg;
              float v = accH[m][n][reg] + accL[m][n][reg]*inv + bb;
              v = gelu_f(v);
              _Float16 hi = (_Float16)v;
              SH[OG_H1HI + e*40 + tt*16 + lm] = hi;
              SH[OG_H1LO + e*40 + tt*16 + lm] = (_Float16)((v-(float)hi)*2048.f);
            }
          }
        }
      }
      __syncthreads();
      h8 bh = *(const h8*)&SH[OG_W2HI + (wid*16+lm)*40 + quad*8];
      h8 bl = *(const h8*)&SH[OG_W2LO + (wid*16+lm)*40 + quad*8];
      #pragma unroll
      for(int m=0;m<4;m++){
        h8 a2h = *(const h8*)&SH[OG_H1HI + (m*16+lm)*40 + quad*8];
        h8 a2l = *(const h8*)&SH[OG_H1LO + (m*16+lm)*40 + quad*8];
        acc2H[m] = __builtin_amdgcn_mfma_f32_16x16x32_f16(a2h, bh, acc2H[m], 0,0,0);
        acc2L[m] = __builtin_amdgcn_mfma_f32_16x16x32_f16(a2h, bl, acc2L[m], 0,0,0);
        acc2L[m] = __builtin_amdgcn_mfma_f32_16x16x32_f16(a2l, bh, acc2L[m], 0,0,0);
      }
      __syncthreads();
    }
  }

  int n2 = wid*16 + lm;
  float bb2 = b2[n2];
  #pragma unroll
  for(int m=0;m<4;m++){
    #pragma unroll
    for(int reg=0;reg<4;reg++){
      int e = m*16 + quad*4 + reg;
      int eg = et0 + e;
      if(eg < eEnd){
        float v = acc2H[m][reg] + acc2L[m][reg]*inv + bb2;
        v *= xlat[(size_t)js[e]*64 + n2];
        atomicAdd(&outev[(size_t)qs[e]*64 + n2], v);
      }
    }
  }
}

// -------- row MLP 64->128(gelu)->64, optional gated epilogue --------
__global__ __launch_bounds__(256) void k_mlp_plain(const float* __restrict__ X,
    const float* __restrict__ W0, const float* __restrict__ b0,
    const float* __restrict__ W1, const float* __restrict__ b1,
    float* __restrict__ Y)
{
  __shared__ float xt[64*16];
  __shared__ float ht[128*16];
  int t = threadIdx.x, r0 = blockIdx.x*16;
  for(int w=t; w<1024; w+=256){ int r=w>>6, c=w&63; xt[c*16+r] = X[(size_t)(r0+r)*64+c]; }
  __syncthreads();
  {
    int hc = t & 127, rg = t >> 7;
    float acc[8]; float bb = b0[hc];
    #pragma unroll
    for(int u=0;u<8;u++) acc[u]=bb;
    for(int i=0;i<64;i++){
      float wv = W0[i*128+hc];
      const float* xp = &xt[i*16 + rg*8];
      float4 x0 = *(const float4*)xp; float4 x1 = *(const float4*)(xp+4);
      acc[0]=fmaf(x0.x,wv,acc[0]); acc[1]=fmaf(x0.y,wv,acc[1]);
      acc[2]=fmaf(x0.z,wv,acc[2]); acc[3]=fmaf(x0.w,wv,acc[3]);
      acc[4]=fmaf(x1.x,wv,acc[4]); acc[5]=fmaf(x1.y,wv,acc[5]);
      acc[6]=fmaf(x1.z,wv,acc[6]); acc[7]=fmaf(x1.w,wv,acc[7]);
    }
    #pragma unroll
    for(int u=0;u<8;u++) ht[hc*16 + rg*8 + u] = gelu_f(acc[u]);
  }
  __syncthreads();
  {
    int oc = t & 63, rg = t >> 6;
    float acc2[4]; float bb = b1[oc];
    #pragma unroll
    for(int u=0;u<4;u++) acc2[u]=bb;
    for(int i=0;i<128;i++){
      float wv = W1[i*64+oc];
      float4 h4v = *(const float4*)&ht[i*16 + rg*4];
      acc2[0]=fmaf(h4v.x,wv,acc2[0]); acc2[1]=fmaf(h4v.y,wv,acc2[1]);
      acc2[2]=fmaf(h4v.z,wv,acc2[2]); acc2[3]=fmaf(h4v.w,wv,acc2[3]);
    }
    #pragma unroll
    for(int u=0;u<4;u++) Y[(size_t)(r0+rg*4+u)*64 + oc] = acc2[u];
  }
}

__global__ __launch_bounds__(256) void k_mlp_gated(const float* __restrict__ X,
    const float* __restrict__ W0, const float* __restrict__ b0,
    const float* __restrict__ W1, const float* __restrict__ b1,
    const float* __restrict__ gwp, const float* __restrict__ gbp,
    float* __restrict__ Y)
{
  __shared__ float xt[64*16];
  __shared__ float ht[128*16];
  int t = threadIdx.x, r0 = blockIdx.x*16;
  for(int w=t; w<1024; w+=256){ int r=w>>6, c=w&63; xt[c*16+r] = X[(size_t)(r0+r)*64+c]; }
  __syncthreads();
  {
    int hc = t & 127, rg = t >> 7;
    float acc[8]; float bb = b0[hc];
    #pragma unroll
    for(int u=0;u<8;u++) acc[u]=bb;
    for(int i=0;i<64;i++){
      float wv = W0[i*128+hc];
      const float* xp = &xt[i*16 + rg*8];
      float4 x0 = *(const float4*)xp; float4 x1 = *(const float4*)(xp+4);
      acc[0]=fmaf(x0.x,wv,acc[0]); acc[1]=fmaf(x0.y,wv,acc[1]);
      acc[2]=fmaf(x0.z,wv,acc[2]); acc[3]=fmaf(x0.w,wv,acc[3]);
      acc[4]=fmaf(x1.x,wv,acc[4]); acc[5]=fmaf(x1.y,wv,acc[5]);
      acc[6]=fmaf(x1.z,wv,acc[6]); acc[7]=fmaf(x1.w,wv,acc[7]);
    }
    #pragma unroll
    for(int u=0;u<8;u++) ht[hc*16 + rg*8 + u] = gelu_f(acc[u]);
  }
  __syncthreads();
  {
    int oc = t & 63, rg = t >> 6;
    float acc2[4]; float bb = b1[oc];
    #pragma unroll
    for(int u=0;u<4;u++) acc2[u]=bb;
    for(int i=0;i<128;i++){
      float wv = W1[i*64+oc];
      float4 h4v = *(const float4*)&ht[i*16 + rg*4];
      acc2[0]=fmaf(h4v.x,wv,acc2[0]); acc2[1]=fmaf(h4v.y,wv,acc2[1]);
      acc2[2]=fmaf(h4v.z,wv,acc2[2]); acc2[3]=fmaf(h4v.w,wv,acc2[3]);
    }
    float gwv = gwp[oc], gbv = gbp[oc];
    #pragma unroll
    for(int u=0;u<4;u++){
      int r = rg*4+u;
      float a = xt[oc*16 + r];
      Y[(size_t)(r0+r)*64 + oc] = gelu_f(acc2[u] + fmaf(a, gwv, gbv));
    }
  }
}

// -------- truncated DFT stages --------
__global__ void k_fz_fwd(const float* __restrict__ h, const float* __restrict__ twc,
                         const float* __restrict__ tws, float* __restrict__ Fr, float* __restrict__ Fi){
  int idx = blockIdx.x*256 + threadIdx.x;
  int c = idx&63, kz=(idx>>6)&7, y=(idx>>9)&31, x=idx>>14;
  const float* hp = h + ((size_t)(x*32+y)*32)*64 + c;
  float re=0.f, im=0.f;
  for(int z=0; z<32; z++){
    float v = hp[(size_t)z*64];
    int k = (kz*z)&31;
    re = fmaf(v, twc[k], re);
    im = fmaf(-v, tws[k], im);
  }
  Fr[idx]=re; Fi[idx]=im;
}

__global__ void k_fy_fwd(const float* __restrict__ Ar, const float* __restrict__ Ai,
                         const float* __restrict__ twc, const float* __restrict__ tws,
                         float* __restrict__ Fr, float* __restrict__ Fi){
  int idx = blockIdx.x*256 + threadIdx.x;
  int c = idx&63, kz=(idx>>6)&7, my=(idx>>9)&15, x=idx>>13;
  int ky = my<8 ? my : my+16;
  const float* pr = Ar + ((size_t)(x*32)*8+kz)*64 + c;
  const float* pi = Ai + ((size_t)(x*32)*8+kz)*64 + c;
  float re=0.f, im=0.f;
  for(int y=0;y<32;y++){
    float a = pr[(size_t)y*512], b = pi[(size_t)y*512];
    int k = (ky*y)&31; float cs=twc[k], sn=tws[k];
    re += a*cs + b*sn;
    im += b*cs - a*sn;
  }
  Fr[idx]=re; Fi[idx]=im;
}

__global__ void k_fx_fwd(const float* __restrict__ Ar, const float* __restrict__ Ai,
                         const float* __restrict__ twc, const float* __restrict__ tws,
                         float* __restrict__ Fr, float* __restrict__ Fi){
  int idx = blockIdx.x*256 + threadIdx.x;
  int c = idx&63, kz=(idx>>6)&7, my=(idx>>9)&15, mx=idx>>13;
  int kx = mx<8 ? mx : mx+16;
  const float* pr = Ar + ((size_t)my*8+kz)*64 + c;
  const float* pi = Ai + ((size_t)my*8+kz)*64 + c;
  float re=0.f, im=0.f;
  for(int x=0;x<32;x++){
    float a = pr[(size_t)x*8192], b = pi[(size_t)x*8192];
    int k = (kx*x)&31; float cs=twc[k], sn=tws[k];
    re += a*cs + b*sn;
    im += b*cs - a*sn;
  }
  Fr[idx]=re; Fi[idx]=im;
}

__global__ void k_smm(const float* __restrict__ Fr, const float* __restrict__ Fi,
                      const float* __restrict__ wlayer,
                      float* __restrict__ Gr, float* __restrict__ Gi){
  int t = threadIdx.x;
  int sub = t>>6, c = t&63;
  int mp = blockIdx.x*4 + sub;
  int kz = mp&7, my=(mp>>3)&15, mx=mp>>7;
  int corner = ((mx>=8)?2:0) | ((my>=8)?1:0);
  int kxp = mx&7, kyp = my&7;
  const float* wp = wlayer + (size_t)(((corner*8+kxp)*8+kyp)*8+kz)*8192;
  __shared__ float fre[4][64], fim[4][64];
  fre[sub][c] = Fr[(size_t)mp*64+c];
  fim[sub][c] = Fi[(size_t)mp*64+c];
  __syncthreads();
  float are=0.f, aim=0.f;
  for(int i=0;i<64;i++){
    float2 wv = *(const float2*)&wp[(size_t)(i*64+c)*2];
    float a = fre[sub][i], b = fim[sub][i];
    are += a*wv.x - b*wv.y;
    aim += a*wv.y + b*wv.x;
  }
  Gr[(size_t)mp*64+c] = are;
  Gi[(size_t)mp*64+c] = aim;
}

__global__ void k_fx_inv(const float* __restrict__ Ar, const float* __restrict__ Ai,
                         const float* __restrict__ twc, const float* __restrict__ tws,
                         float* __restrict__ Fr, float* __restrict__ Fi){
  int idx = blockIdx.x*256 + threadIdx.x;
  int c = idx&63, kz=(idx>>6)&7, my=(idx>>9)&15, x=idx>>13;
  float re=0.f, im=0.f;
  for(int mx=0;mx<16;mx++){
    int kx = mx<8 ? mx : mx+16;
    int k = (kx*x)&31; float cs=twc[k], sn=tws[k];
    float a = Ar[(size_t)((mx*16+my)*8+kz)*64+c];
    float b = Ai[(size_t)((mx*16+my)*8+kz)*64+c];
    re += a*cs - b*sn;
    im += a*sn + b*cs;
  }
  Fr[idx]=re; Fi[idx]=im;
}

__global__ void k_fy_inv(const float* __restrict__ Ar, const float* __restrict__ Ai,
                         const float* __restrict__ twc, const float* __restrict__ tws,
                         float* __restrict__ Fr, float* __restrict__ Fi){
  int idx = blockIdx.x*256 + threadIdx.x;
  int c = idx&63, kz=(idx>>6)&7, y=(idx>>9)&31, x=idx>>14;
  float re=0.f, im=0.f;
  for(int my=0;my<16;my++){
    int ky = my<8 ? my : my+16;
    int k = (ky*y)&31; float cs=twc[k], sn=tws[k];
    float a = Ar[(size_t)((x*16+my)*8+kz)*64+c];
    float b = Ai[(size_t)((x*16+my)*8+kz)*64+c];
    re += a*cs - b*sn;
    im += a*sn + b*cs;
  }
  Fr[idx]=re; Fi[idx]=im;
}

__global__ void k_fz_inv_skip(const float* __restrict__ G2re, const float* __restrict__ G2im,
    const float* __restrict__ h, const float* __restrict__ twc, const float* __restrict__ tws,
    const float* __restrict__ sw, float* __restrict__ a_out)
{
  __shared__ float hrow[4][64];
  int t = threadIdx.x; int c = t&63; int pl = t>>6;
  int p = blockIdx.x*4 + pl;
  int z = p & 31; int xy = p >> 5;
  hrow[pl][c] = h[(size_t)p*64 + c];
  __syncthreads();
  const float* gr = G2re + (size_t)(xy*8)*64 + c;
  const float* gi = G2im + (size_t)(xy*8)*64 + c;
  float acc = gr[0];
  #pragma unroll
  for(int kz=1;kz<8;kz++){
    int k = (kz*z)&31;
    acc += 2.f*(gr[(size_t)kz*64]*twc[k] - gi[(size_t)kz*64]*tws[k]);
  }
  float vfno = acc * (1.f/32768.f);
  float vskip = 0.f;
  for(int i=0;i<64;i++) vskip = fmaf(hrow[pl][i], sw[i*64+c], vskip);
  a_out[(size_t)p*64+c] = gelu_f(vfno + vskip);
}

// -------- projection --------
__global__ __launch_bounds__(256) void k_proj(const float* __restrict__ outev,
    const float* __restrict__ pw0, const float* __restrict__ pb0,
    const float* __restrict__ pw1, const float* __restrict__ pb1,
    float* __restrict__ outp)
{
  __shared__ float msg[8][64];
  __shared__ float red[8][4];
  int t = threadIdx.x; int q0 = blockIdx.x*8;
  for(int w=t; w<512; w+=256){
    int qq=w>>6, o=w&63; int q=q0+qq;
    msg[qq][o] = (q<N_OUT) ? outev[(size_t)q*64+o] : 0.f;
  }
  __syncthreads();
  float p[8]; float bb = pb0[t];
  #pragma unroll
  for(int qq=0;qq<8;qq++) p[qq]=bb;
  for(int o=0;o<64;o++){
    float wv = pw0[o*256+t];
    #pragma unroll
    for(int qq=0;qq<8;qq++) p[qq] = fmaf(msg[qq][o], wv, p[qq]);
  }
  float w1v = pw1[t];
  int lane = t & 63, wid = t >> 6;
  #pragma unroll
  for(int qq=0;qq<8;qq++){
    float v = gelu_f(p[qq]) * w1v;
    for(int d=32; d>=1; d>>=1) v += __shfl_down(v, d, 64);
    if(lane==0) red[qq][wid]=v;
  }
  __syncthreads();
  if(t<8){
    int q = q0+t;
    if(q<N_OUT) outp[q] = red[t][0]+red[t][1]+red[t][2]+red[t][3] + pb1[0];
  }
}

// ==================== host ====================
extern "C" void kernel_launch(void* const* d_in, const int* in_sizes, int n_in,
                              void* d_out, int out_size, void* d_ws, size_t ws_size,
                              hipStream_t stream)
{
  (void)in_sizes; (void)n_in; (void)out_size; (void)ws_size;
  const float* geom = (const float*)d_in[0];
  const float* latq = (const float*)d_in[1];
  const float* outq = (const float*)d_in[2];
  const float* xin  = (const float*)d_in[3];
  const float* ilw  = (const float*)d_in[4];
  const float* ilb  = (const float*)d_in[5];
  const float* ikw0 = (const float*)d_in[6];
  const float* ikb0 = (const float*)d_in[7];
  const float* ikw1 = (const float*)d_in[8];
  const float* ikb1 = (const float*)d_in[9];
  const float* ikw2 = (const float*)d_in[10];
  const float* ikb2 = (const float*)d_in[11];
  const float* ikw3 = (const float*)d_in[12];
  const float* ikb3 = (const float*)d_in[13];
  const float* lw0  = (const float*)d_in[14];
  const float* lb0  = (const float*)d_in[15];
  const float* lw1  = (const float*)d_in[16];
  const float* lb1  = (const float*)d_in[17];
  const float* specw= (const float*)d_in[18];
  const float* skw  = (const float*)d_in[19];
  const float* gw   = (const float*)d_in[20];
  const float* gb   = (const float*)d_in[21];
  const float* cw0  = (const float*)d_in[22];
  const float* cb0  = (const float*)d_in[23];
  const float* cw1  = (const float*)d_in[24];
  const float* cb1  = (const float*)d_in[25];
  const float* okw0 = (const float*)d_in[26];
  const float* okb0 = (const float*)d_in[27];
  const float* okw1 = (const float*)d_in[28];
  const float* okb1 = (const float*)d_in[29];
  const float* okw2 = (const float*)d_in[30];
  const float* okb2 = (const float*)d_in[31];
  const float* pw0  = (const float*)d_in[32];
  const float* pb0  = (const float*)d_in[33];
  const float* pw1  = (const float*)d_in[34];
  const float* pb1  = (const float*)d_in[35];
  const int* iidx = (const int*)d_in[36];
  const int* oidx = (const int*)d_in[37];
  float* outp = (float*)d_out;
  float* ws = (float*)d_ws;

  size_t off = 0;
  float* F_IN = ws + off; off += (size_t)N_IN*64;
  float* AIN  = ws + off; off += (size_t)N_IN*80;
  float* BIN_ = ws + off; off += (size_t)N_LQ*80;
  float* AOUT = ws + off; off += (size_t)N_LQ*512;
  float* BOUT = ws + off; off += (size_t)N_OUT*512;
  float* HBUF = ws + off; off += (size_t)N_LQ*64;
  float* ABUF = ws + off; off += (size_t)N_LQ*64;
  float* FZr = ws+off; off+=524288; float* FZi = ws+off; off+=524288;
  float* FYr = ws+off; off+=262144; float* FYi = ws+off; off+=262144;
  float* FXr = ws+off; off+=131072; float* FXi = ws+off; off+=131072;
  float* GMr = ws+off; off+=131072; float* GMi = ws+off; off+=131072;
  float* G1r = ws+off; off+=262144; float* G1i = ws+off; off+=262144;
  float* G2r = ws+off; off+=524288; float* G2i = ws+off; off+=524288;
  float* OUTEV = ws+off; off += (size_t)N_OUT*64;
  float* TWC = ws+off; off+=32; float* TWS = ws+off; off+=32;
  off = (off + 3) & ~(size_t)3;
  _Float16* P = (_Float16*)(ws + off);
  _Float16 *W1h = P,          *W1l = P+131072;
  _Float16 *W2h = P+262144,   *W2l = P+278528;
  _Float16 *I1h = P+294912,   *I1l = P+301312;
  _Float16 *I2h = P+307712,   *I2l = P+314112;
  _Float16 *I3h = P+320512,   *I3l = P+325632;

  k_twiddle<<<1, 64, 0, stream>>>(TWC, TWS);
  k_prep<<<512, 256, 0, stream>>>(okw1, okw2, ikw1, ikw2, ikw3,
                                  W1h, W1l, W2h, W2l, I1h, I1l, I2h, I2l, I3h, I3l);
  k_lift_in<<<(N_IN*64)/256, 256, 0, stream>>>(xin, ilw, ilb, F_IN);
  k_embed_partial<80,false><<<N_IN/8, 256, 0, stream>>>(geom, N_IN, ikw0, 0, (const float*)nullptr, AIN);
  k_embed_partial<80,true ><<<N_LQ/8, 256, 0, stream>>>(latq, N_LQ, ikw0, 96, ikb0, BIN_);
  k_embed_partial<512,false><<<N_LQ/8, 256, 0, stream>>>(latq, N_LQ, okw0, 0, (const float*)nullptr, AOUT);
  k_embed_partial<512,true ><<<(N_OUT+7)/8, 256, 0, stream>>>(outq, N_OUT, okw0, 96, okb0, BOUT);

  hipMemsetAsync(HBUF, 0, (size_t)N_LQ*64*sizeof(float), stream);
  k_gino<<<(N_LQ*KNB)/64, 256, 0, stream>>>(AIN, BIN_, F_IN, iidx,
                                            I1h, I1l, ikb1, I2h, I2l, ikb2, I3h, I3l, ikb3, HBUF);
  k_mlp_plain<<<N_LQ/16, 256, 0, stream>>>(HBUF, lw0, lb0, lw1, lb1, HBUF);

  for(int l=0;l<4;l++){
    k_fz_fwd<<<2048,256,0,stream>>>(HBUF, TWC, TWS, FZr, FZi);
    k_fy_fwd<<<1024,256,0,stream>>>(FZr, FZi, TWC, TWS, FYr, FYi);
    k_fx_fwd<<<512,256,0,stream>>>(FYr, FYi, TWC, TWS, FXr, FXi);
    k_smm<<<512,256,0,stream>>>(FXr, FXi, specw + (size_t)l*16777216, GMr, GMi);
    k_fx_inv<<<1024,256,0,stream>>>(GMr, GMi, TWC, TWS, G1r, G1i);
    k_fy_inv<<<2048,256,0,stream>>>(G1r, G1i, TWC, TWS, G2r, G2i);
    k_fz_inv_skip<<<8192,256,0,stream>>>(G2r, G2i, HBUF, TWC, TWS, skw + (size_t)l*4096, ABUF);
    k_mlp_gated<<<N_LQ/16,256,0,stream>>>(ABUF, cw0 + (size_t)l*8192, cb0 + l*128,
                                          cw1 + (size_t)l*8192, cb1 + l*64,
                                          gw + l*64, gb + l*64, HBUF);
  }

  hipMemsetAsync(OUTEV, 0, (size_t)N_OUT*64*sizeof(float), stream);
  k_ogno<<<(N_OUT*KNB + 63)/64, 256, 0, stream>>>(AOUT, BOUT, oidx,
                                                  W1h, W1l, okb1, W2h, W2l, okb2,
                                                  HBUF, OUTEV, N_OUT*KNB);
  k_proj<<<(N_OUT+7)/8, 256, 0, stream>>>(OUTEV, pw0, pb0, pw1, pb1, outp);
}

// Round 4
// 1860.862 us; speedup vs baseline: 1.5353x; 1.0518x over previous
//
#include <hip/hip_runtime.h>
#include <math.h>

// GINO forward. f32 everywhere except GNO MLP GEMMs, which use split-f16
// MFMA (hi + lo*2^-11, 3 MFMAs per product pair -> ~2^-22 relative error).
#define N_IN   100000
#define N_LQ   32768
#define N_OUT  30000
#define KNB    10

typedef _Float16 h8 __attribute__((ext_vector_type(8)));
typedef _Float16 h4 __attribute__((ext_vector_type(4)));
typedef float    v4f __attribute__((ext_vector_type(4)));

__device__ __forceinline__ float gelu_f(float x){
  float t = 0.79788456080286536f * (x + 0.044715f*x*x*x);
  t = fminf(fmaxf(t, -15.f), 15.f);
  float e = __expf(2.f*t);
  float th = __fdividef(e - 1.f, e + 1.f);
  return 0.5f*x*(1.f + th);
}

// -------- twiddles --------
__global__ void k_twiddle(float* __restrict__ twc, float* __restrict__ tws){
  int t = threadIdx.x;
  if(t < 32){
    double a = (double)t * 0.19634954084936207; // 2*pi/32
    twc[t] = (float)cos(a);
    tws[t] = (float)sin(a);
  }
}

// -------- weight split/transpose for MFMA kernels --------
// W1: okw1 [512][256] -> W1T[n(256)][k(512)] hi/lo
// W2: okw2 [256][64]  -> W2T[n(64)][k(256)]  hi/lo
// I1/I2: ikw1/2 [80][80] -> [n(80)][k(80)] ; I3: ikw3 [80][64] -> [n(64)][k(80)]
__global__ void k_prep(const float* __restrict__ okw1, const float* __restrict__ okw2,
                       const float* __restrict__ ikw1, const float* __restrict__ ikw2,
                       const float* __restrict__ ikw3,
                       _Float16* W1h, _Float16* W1l, _Float16* W2h, _Float16* W2l,
                       _Float16* I1h, _Float16* I1l, _Float16* I2h, _Float16* I2l,
                       _Float16* I3h, _Float16* I3l)
{
  int idx = blockIdx.x*256 + threadIdx.x;
  if(idx < 512*256){
    int k = idx>>8, n = idx&255;
    float v = okw1[idx];
    _Float16 hi = (_Float16)v;
    W1h[n*512+k] = hi; W1l[n*512+k] = (_Float16)((v-(float)hi)*2048.f);
  }
  if(idx < 256*64){
    int k = idx>>6, n = idx&63;
    float v = okw2[idx];
    _Float16 hi = (_Float16)v;
    W2h[n*256+k] = hi; W2l[n*256+k] = (_Float16)((v-(float)hi)*2048.f);
  }
  if(idx < 6400){
    int n = idx/80, k = idx - n*80;
    float v = ikw1[k*80+n];
    _Float16 hi = (_Float16)v;
    I1h[n*80+k] = hi; I1l[n*80+k] = (_Float16)((v-(float)hi)*2048.f);
    float v2 = ikw2[k*80+n];
    _Float16 hi2 = (_Float16)v2;
    I2h[n*80+k] = hi2; I2l[n*80+k] = (_Float16)((v2-(float)hi2)*2048.f);
  }
  if(idx < 5120){
    int n = idx/80, k = idx - n*80;
    float v = ikw3[k*64+n];
    _Float16 hi = (_Float16)v;
    I3h[n*80+k] = hi; I3l[n*80+k] = (_Float16)((v-(float)hi)*2048.f);
  }
}

// -------- f_in = x @ in_lift_w + b --------
__global__ void k_lift_in(const float* __restrict__ x, const float* __restrict__ w,
                          const float* __restrict__ b, float* __restrict__ f){
  int i = blockIdx.x*256 + threadIdx.x;
  if(i >= N_IN*64) return;
  int p = i>>6, c = i&63;
  float v = b[c];
  v = fmaf(x[p*3+0], w[c],      v);
  v = fmaf(x[p*3+1], w[64+c],   v);
  v = fmaf(x[p*3+2], w[128+c],  v);
  f[i] = v;
}

// -------- sinusoidal embed (f64 angles) + partial matmul vs W0 rows --------
template<int COLS, bool BIAS>
__global__ __launch_bounds__(256) void k_embed_partial(
    const float* __restrict__ coords, int npts,
    const float* __restrict__ W, int roff,
    const float* __restrict__ bias, float* __restrict__ outp)
{
  __shared__ float emb[96*8];
  int p0 = blockIdx.x*8;
  int t  = threadIdx.x;
  for(int w = t; w < 384; w += 256){
    int pl = w / 48, s = w - pl*48;
    int d = s >> 4, fi = s & 15;
    int p = p0 + pl;
    float cd = (p < npts) ? coords[(size_t)p*3 + d] : 0.f;
    double f = exp((double)fi * 0.5756462732485115); // ln(10000)/16
    double a = (double)cd * f;
    double sn, cs; sincos(a, &sn, &cs);
    emb[((d<<5)+fi)*8 + pl]      = (float)sn;
    emb[((d<<5)+16+fi)*8 + pl]   = (float)cs;
  }
  __syncthreads();
  for(int c = t; c < COLS; c += 256){
    float acc[8];
    float bb = BIAS ? bias[c] : 0.f;
    #pragma unroll
    for(int u=0;u<8;u++) acc[u] = bb;
    for(int i=0;i<96;i++){
      float wv = W[(size_t)(roff+i)*COLS + c];
      const float* ep = &emb[i*8];
      float4 e0 = *(const float4*)ep;
      float4 e1 = *(const float4*)(ep+4);
      acc[0]=fmaf(e0.x,wv,acc[0]); acc[1]=fmaf(e0.y,wv,acc[1]);
      acc[2]=fmaf(e0.z,wv,acc[2]); acc[3]=fmaf(e0.w,wv,acc[3]);
      acc[4]=fmaf(e1.x,wv,acc[4]); acc[5]=fmaf(e1.y,wv,acc[5]);
      acc[6]=fmaf(e1.z,wv,acc[6]); acc[7]=fmaf(e1.w,wv,acc[7]);
    }
    #pragma unroll
    for(int u=0;u<8;u++){
      int p = p0+u;
      if(p < npts) outp[(size_t)p*COLS + c] = acc[u];
    }
  }
}

// ==================== input GNO via split-f16 MFMA ====================
// 64 edges/block, MLP 80->80->80->64 (K chunks 32,32,16), mean-reduce via atomics.
#define GI_HAHI 0
#define GI_HALO 5632
#define GI_WHI  11264
#define GI_WLO  14464
__global__ __launch_bounds__(256,2) void k_gino(
    const float* __restrict__ Ain, const float* __restrict__ Bin,
    const float* __restrict__ f_in, const int* __restrict__ iidx,
    const _Float16* __restrict__ I1h, const _Float16* __restrict__ I1l, const float* __restrict__ b1,
    const _Float16* __restrict__ I2h, const _Float16* __restrict__ I2l, const float* __restrict__ b2,
    const _Float16* __restrict__ I3h, const _Float16* __restrict__ I3l, const float* __restrict__ b3,
    float* __restrict__ in_p)
{
  __shared__ _Float16 SG[17664];
  __shared__ int js[64]; __shared__ int qs[64];
  int t = threadIdx.x;
  int wid = t>>6, lane = t&63, quad = lane>>4, lm = lane&15;
  int et0 = blockIdx.x*64;
  if(t<64){ js[t] = iidx[et0+t]; qs[t] = (et0+t)/KNB; }
  __syncthreads();

  // L0 staging: gelu(Ain[j] + Bin[q]) split -> hA
  {
    int e = t>>2, k4 = t&3;
    size_t ja = (size_t)js[e]*80, qa = (size_t)qs[e]*80;
    #pragma unroll
    for(int u=0;u<3;u++){
      int kl = k4*8 + u*32;
      if(kl < 80){
        float4 a0 = *(const float4*)(Ain + ja + kl);
        float4 a1 = *(const float4*)(Ain + ja + kl + 4);
        float4 c0 = *(const float4*)(Bin + qa + kl);
        float4 c1 = *(const float4*)(Bin + qa + kl + 4);
        float vv[8] = {a0.x+c0.x, a0.y+c0.y, a0.z+c0.z, a0.w+c0.w,
                       a1.x+c1.x, a1.y+c1.y, a1.z+c1.z, a1.w+c1.w};
        h8 hh, ll;
        #pragma unroll
        for(int q8=0;q8<8;q8++){
          float g = gelu_f(vv[q8]);
          _Float16 hi = (_Float16)g;
          hh[q8] = hi; ll[q8] = (_Float16)((g-(float)hi)*2048.f);
        }
        *(h8*)&SG[GI_HAHI + e*88 + kl] = hh;
        *(h8*)&SG[GI_HALO + e*88 + kl] = ll;
      }
    }
  }

  const float inv = 4.8828125e-4f;
  const _Float16* whp[3] = {I1h, I2h, I3h};
  const _Float16* wlp[3] = {I1l, I2l, I3l};
  const float*    bsp[3] = {b1, b2, b3};
  v4f aH[5], aL[5];

  for(int l=0;l<3;l++){
    int NT = (l==2)?4:5;
    const _Float16* wh = whp[l];
    const _Float16* wl = wlp[l];
    #pragma unroll
    for(int n=0;n<5;n++){ aH[n] = (v4f)(0.f); aL[n] = (v4f)(0.f); }
    for(int c=0;c<3;c++){
      int kb = c*32;
      int per = (c==2)?2:4;
      int units = NT*16*per;
      __syncthreads();
      for(int u=t; u<units; u+=256){
        int n = u/per, kh = (u - n*per)*8;
        float4 rh = *(const float4*)(wh + n*80 + kb + kh);
        float4 rl = *(const float4*)(wl + n*80 + kb + kh);
        *(float4*)&SG[GI_WHI + n*40 + kh] = rh;
        *(float4*)&SG[GI_WLO + n*40 + kh] = rl;
      }
      __syncthreads();
      int arow = (wid*16+lm)*88;
      if(c<2){
        h8 ah = *(const h8*)&SG[GI_HAHI + arow + kb + quad*8];
        h8 al = *(const h8*)&SG[GI_HALO + arow + kb + quad*8];
        for(int n=0;n<NT;n++){
          int brow = (n*16+lm)*40;
          h8 bh = *(const h8*)&SG[GI_WHI + brow + quad*8];
          h8 bl = *(const h8*)&SG[GI_WLO + brow + quad*8];
          aH[n] = __builtin_amdgcn_mfma_f32_16x16x32_f16(ah, bh, aH[n], 0,0,0);
          aL[n] = __builtin_amdgcn_mfma_f32_16x16x32_f16(ah, bl, aL[n], 0,0,0);
          aL[n] = __builtin_amdgcn_mfma_f32_16x16x32_f16(al, bh, aL[n], 0,0,0);
        }
      } else {
        h4 ah = *(const h4*)&SG[GI_HAHI + arow + 64 + quad*4];
        h4 al = *(const h4*)&SG[GI_HALO + arow + 64 + quad*4];
        for(int n=0;n<NT;n++){
          int brow = (n*16+lm)*40;
          h4 bh = *(const h4*)&SG[GI_WHI + brow + quad*4];
          h4 bl = *(const h4*)&SG[GI_WLO + brow + quad*4];
          aH[n] = __builtin_amdgcn_mfma_f32_16x16x16f16(ah, bh, aH[n], 0,0,0);
          aL[n] = __builtin_amdgcn_mfma_f32_16x16x16f16(ah, bl, aL[n], 0,0,0);
          aL[n] = __builtin_amdgcn_mfma_f32_16x16x16f16(al, bh, aL[n], 0,0,0);
        }
      }
    }
    if(l<2){
      for(int n=0;n<NT;n++){
        float bb = bsp[l][n*16+lm];
        #pragma unroll
        for(int reg=0;reg<4;reg++){
          int e = wid*16 + quad*4 + reg;
          float v = aH[n][reg] + aL[n][reg]*inv + bb;
          v = gelu_f(v);
          _Float16 hi = (_Float16)v;
          SG[GI_HAHI + e*88 + n*16+lm] = hi;
          SG[GI_HALO + e*88 + n*16+lm] = (_Float16)((v-(float)hi)*2048.f);
        }
      }
    } else {
      for(int n=0;n<NT;n++){
        int col = n*16+lm;
        float bb = bsp[2][col];
        #pragma unroll
        for(int reg=0;reg<4;reg++){
          int e = wid*16 + quad*4 + reg;
          float v = aH[n][reg] + aL[n][reg]*inv + bb;
          v *= f_in[(size_t)js[e]*64 + col] * 0.1f;
          atomicAdd(&in_p[(size_t)qs[e]*64 + col], v);
        }
      }
    }
  }
}

// ==================== output GNO via split-f16 MFMA (fused, v2) ====================
// 64 edges/block. No LDS staging for W1/W2 (direct coalesced 16B-frag global
// loads, L2-resident). A-gather register-prefetched one chunk ahead.
// GEMM1: [64 x 256] K=512 -> H1 in LDS (stride 264) -> GEMM2: [64 x 64] K=256,
// barrier-free -> *xlat[j] -> atomicAdd.
__global__ __launch_bounds__(256,2) void k_ogno(
    const float* __restrict__ Aout, const float* __restrict__ Bout,
    const int* __restrict__ oidx,
    const _Float16* __restrict__ W1h, const _Float16* __restrict__ W1l,
    const float* __restrict__ b1,
    const _Float16* __restrict__ W2h, const _Float16* __restrict__ W2l,
    const float* __restrict__ b2,
    const float* __restrict__ xlat, float* __restrict__ outev, int eEnd)
{
  __shared__ _Float16 SH[33792];   // GEMM1: A hi[0..2047], lo[2048..4095]; then H1 [64][264] x2
  __shared__ int js[64]; __shared__ int qs[64];
  int t = threadIdx.x;
  int wid = t>>6, lane = t&63, quad = lane>>4, lm = lane&15;
  int et0 = blockIdx.x*64;
  if(t<64){
    int ec = et0+t; if(ec >= eEnd) ec = eEnd-1;
    js[t] = oidx[ec]; qs[t] = ec/KNB;
  }
  __syncthreads();

  v4f accH[4][4], accL[4][4];
  #pragma unroll
  for(int m=0;m<4;m++)
    #pragma unroll
    for(int n=0;n<4;n++){ accH[m][n] = (v4f)(0.f); accL[m][n] = (v4f)(0.f); }

  int se = t>>2, skl = (t&3)*8;
  const float* pa = Aout + (size_t)js[se]*512 + skl;
  const float* pb = Bout + (size_t)qs[se]*512 + skl;

  float4 cA0 = *(const float4*)(pa);
  float4 cA1 = *(const float4*)(pa+4);
  float4 cB0 = *(const float4*)(pb);
  float4 cB1 = *(const float4*)(pb+4);

  #pragma unroll 1
  for(int kk=0; kk<512; kk+=32){
    // stage A chunk from prefetched regs: gelu(A+B) split -> LDS [64][32] hi/lo
    {
      float vv[8] = {cA0.x+cB0.x, cA0.y+cB0.y, cA0.z+cB0.z, cA0.w+cB0.w,
                     cA1.x+cB1.x, cA1.y+cB1.y, cA1.z+cB1.z, cA1.w+cB1.w};
      h8 hh, ll;
      #pragma unroll
      for(int q8=0;q8<8;q8++){
        float g = gelu_f(vv[q8]);
        _Float16 hi = (_Float16)g;
        hh[q8] = hi; ll[q8] = (_Float16)((g-(float)hi)*2048.f);
      }
      *(h8*)&SH[se*32 + skl] = hh;
      *(h8*)&SH[2048 + se*32 + skl] = ll;
    }
    // prefetch next chunk (in flight across MFMA phase; drained at trailing sync)
    if(kk < 480){
      cA0 = *(const float4*)(pa + kk + 32);
      cA1 = *(const float4*)(pa + kk + 36);
      cB0 = *(const float4*)(pb + kk + 32);
      cB1 = *(const float4*)(pb + kk + 36);
    }
    __syncthreads();
    h8 ah[4], al[4], bh[4], bl[4];
    #pragma unroll
    for(int m=0;m<4;m++){
      ah[m] = *(const h8*)&SH[(m*16+lm)*32 + quad*8];
      al[m] = *(const h8*)&SH[2048 + (m*16+lm)*32 + quad*8];
    }
    #pragma unroll
    for(int n=0;n<4;n++){
      size_t off = (size_t)((wid*4+n)*16+lm)*512 + kk + quad*8;
      bh[n] = *(const h8*)(W1h + off);
      bl[n] = *(const h8*)(W1l + off);
    }
    #pragma unroll
    for(int n=0;n<4;n++)
      #pragma unroll
      for(int m=0;m<4;m++)
        accH[m][n] = __builtin_amdgcn_mfma_f32_16x16x32_f16(ah[m], bh[n], accH[m][n], 0,0,0);
    #pragma unroll
    for(int n=0;n<4;n++)
      #pragma unroll
      for(int m=0;m<4;m++)
        accL[m][n] = __builtin_amdgcn_mfma_f32_16x16x32_f16(ah[m], bl[n], accL[m][n], 0,0,0);
    #pragma unroll
    for(int n=0;n<4;n++)
      #pragma unroll
      for(int m=0;m<4;m++)
        accL[m][n] = __builtin_amdgcn_mfma_f32_16x16x32_f16(al[m], bh[n], accL[m][n], 0,0,0);
    __syncthreads();
  }

  const float inv = 4.8828125e-4f;
  // H1 = gelu(GEMM1 + b1), split, to LDS [64 e][264 stride], comps at 0 / 16896
  #pragma unroll
  for(int n=0;n<4;n++){
    int col = (wid*4+n)*16 + lm;
    float bb = b1[col];
    #pragma unroll
    for(int m=0;m<4;m++){
      #pragma unroll
      for(int reg=0;reg<4;reg++){
        int e = m*16 + quad*4 + reg;
        float v = accH[m][n][reg] + accL[m][n][reg]*inv + bb;
        v = gelu_f(v);
        _Float16 hi = (_Float16)v;
        SH[e*264 + col] = hi;
        SH[16896 + e*264 + col] = (_Float16)((v-(float)hi)*2048.f);
      }
    }
  }
  __syncthreads();

  // GEMM2: barrier-free; W2 fragments direct from global (L2-hot)
  v4f acc2H[4], acc2L[4];
  #pragma unroll
  for(int m=0;m<4;m++){ acc2H[m] = (v4f)(0.f); acc2L[m] = (v4f)(0.f); }
  int n2 = wid*16 + lm;
  #pragma unroll
  for(int c=0;c<8;c++){
    int ksub = c*32;
    size_t woff = (size_t)n2*256 + ksub + quad*8;
    h8 bh2 = *(const h8*)(W2h + woff);
    h8 bl2 = *(const h8*)(W2l + woff);
    #pragma unroll
    for(int m=0;m<4;m++){
      h8 a2h = *(const h8*)&SH[(m*16+lm)*264 + ksub + quad*8];
      h8 a2l = *(const h8*)&SH[16896 + (m*16+lm)*264 + ksub + quad*8];
      acc2H[m] = __builtin_amdgcn_mfma_f32_16x16x32_f16(a2h, bh2, acc2H[m], 0,0,0);
      acc2L[m] = __builtin_amdgcn_mfma_f32_16x16x32_f16(a2h, bl2, acc2L[m], 0,0,0);
      acc2L[m] = __builtin_amdgcn_mfma_f32_16x16x32_f16(a2l, bh2, acc2L[m], 0,0,0);
    }
  }

  // epilogue: +b2, * xlat[j], atomic scatter-add into OUTEV[q]
  float bb2 = b2[n2];
  #pragma unroll
  for(int m=0;m<4;m++){
    #pragma unroll
    for(int reg=0;reg<4;reg++){
      int e = m*16 + quad*4 + reg;
      int eg = et0 + e;
      if(eg < eEnd){
        float v = acc2H[m][reg] + acc2L[m][reg]*inv + bb2;
        v *= xlat[(size_t)js[e]*64 + n2];
        atomicAdd(&outev[(size_t)qs[e]*64 + n2], v);
      }
    }
  }
}

// -------- row MLP 64->128(gelu)->64, optional gated epilogue --------
__global__ __launch_bounds__(256) void k_mlp_plain(const float* __restrict__ X,
    const float* __restrict__ W0, const float* __restrict__ b0,
    const float* __restrict__ W1, const float* __restrict__ b1,
    float* __restrict__ Y)
{
  __shared__ float xt[64*16];
  __shared__ float ht[128*16];
  int t = threadIdx.x, r0 = blockIdx.x*16;
  for(int w=t; w<1024; w+=256){ int r=w>>6, c=w&63; xt[c*16+r] = X[(size_t)(r0+r)*64+c]; }
  __syncthreads();
  {
    int hc = t & 127, rg = t >> 7;
    float acc[8]; float bb = b0[hc];
    #pragma unroll
    for(int u=0;u<8;u++) acc[u]=bb;
    for(int i=0;i<64;i++){
      float wv = W0[i*128+hc];
      const float* xp = &xt[i*16 + rg*8];
      float4 x0 = *(const float4*)xp; float4 x1 = *(const float4*)(xp+4);
      acc[0]=fmaf(x0.x,wv,acc[0]); acc[1]=fmaf(x0.y,wv,acc[1]);
      acc[2]=fmaf(x0.z,wv,acc[2]); acc[3]=fmaf(x0.w,wv,acc[3]);
      acc[4]=fmaf(x1.x,wv,acc[4]); acc[5]=fmaf(x1.y,wv,acc[5]);
      acc[6]=fmaf(x1.z,wv,acc[6]); acc[7]=fmaf(x1.w,wv,acc[7]);
    }
    #pragma unroll
    for(int u=0;u<8;u++) ht[hc*16 + rg*8 + u] = gelu_f(acc[u]);
  }
  __syncthreads();
  {
    int oc = t & 63, rg = t >> 6;
    float acc2[4]; float bb = b1[oc];
    #pragma unroll
    for(int u=0;u<4;u++) acc2[u]=bb;
    for(int i=0;i<128;i++){
      float wv = W1[i*64+oc];
      float4 h4v = *(const float4*)&ht[i*16 + rg*4];
      acc2[0]=fmaf(h4v.x,wv,acc2[0]); acc2[1]=fmaf(h4v.y,wv,acc2[1]);
      acc2[2]=fmaf(h4v.z,wv,acc2[2]); acc2[3]=fmaf(h4v.w,wv,acc2[3]);
    }
    #pragma unroll
    for(int u=0;u<4;u++) Y[(size_t)(r0+rg*4+u)*64 + oc] = acc2[u];
  }
}

__global__ __launch_bounds__(256) void k_mlp_gated(const float* __restrict__ X,
    const float* __restrict__ W0, const float* __restrict__ b0,
    const float* __restrict__ W1, const float* __restrict__ b1,
    const float* __restrict__ gwp, const float* __restrict__ gbp,
    float* __restrict__ Y)
{
  __shared__ float xt[64*16];
  __shared__ float ht[128*16];
  int t = threadIdx.x, r0 = blockIdx.x*16;
  for(int w=t; w<1024; w+=256){ int r=w>>6, c=w&63; xt[c*16+r] = X[(size_t)(r0+r)*64+c]; }
  __syncthreads();
  {
    int hc = t & 127, rg = t >> 7;
    float acc[8]; float bb = b0[hc];
    #pragma unroll
    for(int u=0;u<8;u++) acc[u]=bb;
    for(int i=0;i<64;i++){
      float wv = W0[i*128+hc];
      const float* xp = &xt[i*16 + rg*8];
      float4 x0 = *(const float4*)xp; float4 x1 = *(const float4*)(xp+4);
      acc[0]=fmaf(x0.x,wv,acc[0]); acc[1]=fmaf(x0.y,wv,acc[1]);
      acc[2]=fmaf(x0.z,wv,acc[2]); acc[3]=fmaf(x0.w,wv,acc[3]);
      acc[4]=fmaf(x1.x,wv,acc[4]); acc[5]=fmaf(x1.y,wv,acc[5]);
      acc[6]=fmaf(x1.z,wv,acc[6]); acc[7]=fmaf(x1.w,wv,acc[7]);
    }
    #pragma unroll
    for(int u=0;u<8;u++) ht[hc*16 + rg*8 + u] = gelu_f(acc[u]);
  }
  __syncthreads();
  {
    int oc = t & 63, rg = t >> 6;
    float acc2[4]; float bb = b1[oc];
    #pragma unroll
    for(int u=0;u<4;u++) acc2[u]=bb;
    for(int i=0;i<128;i++){
      float wv = W1[i*64+oc];
      float4 h4v = *(const float4*)&ht[i*16 + rg*4];
      acc2[0]=fmaf(h4v.x,wv,acc2[0]); acc2[1]=fmaf(h4v.y,wv,acc2[1]);
      acc2[2]=fmaf(h4v.z,wv,acc2[2]); acc2[3]=fmaf(h4v.w,wv,acc2[3]);
    }
    float gwv = gwp[oc], gbv = gbp[oc];
    #pragma unroll
    for(int u=0;u<4;u++){
      int r = rg*4+u;
      float a = xt[oc*16 + r];
      Y[(size_t)(r0+r)*64 + oc] = gelu_f(acc2[u] + fmaf(a, gwv, gbv));
    }
  }
}

// -------- truncated DFT stages --------
__global__ void k_fz_fwd(const float* __restrict__ h, const float* __restrict__ twc,
                         const float* __restrict__ tws, float* __restrict__ Fr, float* __restrict__ Fi){
  int idx = blockIdx.x*256 + threadIdx.x;
  int c = idx&63, kz=(idx>>6)&7, y=(idx>>9)&31, x=idx>>14;
  const float* hp = h + ((size_t)(x*32+y)*32)*64 + c;
  float re=0.f, im=0.f;
  for(int z=0; z<32; z++){
    float v = hp[(size_t)z*64];
    int k = (kz*z)&31;
    re = fmaf(v, twc[k], re);
    im = fmaf(-v, tws[k], im);
  }
  Fr[idx]=re; Fi[idx]=im;
}

__global__ void k_fy_fwd(const float* __restrict__ Ar, const float* __restrict__ Ai,
                         const float* __restrict__ twc, const float* __restrict__ tws,
                         float* __restrict__ Fr, float* __restrict__ Fi){
  int idx = blockIdx.x*256 + threadIdx.x;
  int c = idx&63, kz=(idx>>6)&7, my=(idx>>9)&15, x=idx>>13;
  int ky = my<8 ? my : my+16;
  const float* pr = Ar + ((size_t)(x*32)*8+kz)*64 + c;
  const float* pi = Ai + ((size_t)(x*32)*8+kz)*64 + c;
  float re=0.f, im=0.f;
  for(int y=0;y<32;y++){
    float a = pr[(size_t)y*512], b = pi[(size_t)y*512];
    int k = (ky*y)&31; float cs=twc[k], sn=tws[k];
    re += a*cs + b*sn;
    im += b*cs - a*sn;
  }
  Fr[idx]=re; Fi[idx]=im;
}

__global__ void k_fx_fwd(const float* __restrict__ Ar, const float* __restrict__ Ai,
                         const float* __restrict__ twc, const float* __restrict__ tws,
                         float* __restrict__ Fr, float* __restrict__ Fi){
  int idx = blockIdx.x*256 + threadIdx.x;
  int c = idx&63, kz=(idx>>6)&7, my=(idx>>9)&15, mx=idx>>13;
  int kx = mx<8 ? mx : mx+16;
  const float* pr = Ar + ((size_t)my*8+kz)*64 + c;
  const float* pi = Ai + ((size_t)my*8+kz)*64 + c;
  float re=0.f, im=0.f;
  for(int x=0;x<32;x++){
    float a = pr[(size_t)x*8192], b = pi[(size_t)x*8192];
    int k = (kx*x)&31; float cs=twc[k], sn=tws[k];
    re += a*cs + b*sn;
    im += b*cs - a*sn;
  }
  Fr[idx]=re; Fi[idx]=im;
}

__global__ void k_smm(const float* __restrict__ Fr, const float* __restrict__ Fi,
                      const float* __restrict__ wlayer,
                      float* __restrict__ Gr, float* __restrict__ Gi){
  int t = threadIdx.x;
  int sub = t>>6, c = t&63;
  int mp = blockIdx.x*4 + sub;
  int kz = mp&7, my=(mp>>3)&15, mx=mp>>7;
  int corner = ((mx>=8)?2:0) | ((my>=8)?1:0);
  int kxp = mx&7, kyp = my&7;
  const float* wp = wlayer + (size_t)(((corner*8+kxp)*8+kyp)*8+kz)*8192;
  __shared__ float fre[4][64], fim[4][64];
  fre[sub][c] = Fr[(size_t)mp*64+c];
  fim[sub][c] = Fi[(size_t)mp*64+c];
  __syncthreads();
  float are=0.f, aim=0.f;
  for(int i=0;i<64;i++){
    float2 wv = *(const float2*)&wp[(size_t)(i*64+c)*2];
    float a = fre[sub][i], b = fim[sub][i];
    are += a*wv.x - b*wv.y;
    aim += a*wv.y + b*wv.x;
  }
  Gr[(size_t)mp*64+c] = are;
  Gi[(size_t)mp*64+c] = aim;
}

__global__ void k_fx_inv(const float* __restrict__ Ar, const float* __restrict__ Ai,
                         const float* __restrict__ twc, const float* __restrict__ tws,
                         float* __restrict__ Fr, float* __restrict__ Fi){
  int idx = blockIdx.x*256 + threadIdx.x;
  int c = idx&63, kz=(idx>>6)&7, my=(idx>>9)&15, x=idx>>13;
  float re=0.f, im=0.f;
  for(int mx=0;mx<16;mx++){
    int kx = mx<8 ? mx : mx+16;
    int k = (kx*x)&31; float cs=twc[k], sn=tws[k];
    float a = Ar[(size_t)((mx*16+my)*8+kz)*64+c];
    float b = Ai[(size_t)((mx*16+my)*8+kz)*64+c];
    re += a*cs - b*sn;
    im += a*sn + b*cs;
  }
  Fr[idx]=re; Fi[idx]=im;
}

__global__ void k_fy_inv(const float* __restrict__ Ar, const float* __restrict__ Ai,
                         const float* __restrict__ twc, const float* __restrict__ tws,
                         float* __restrict__ Fr, float* __restrict__ Fi){
  int idx = blockIdx.x*256 + threadIdx.x;
  int c = idx&63, kz=(idx>>6)&7, y=(idx>>9)&31, x=idx>>14;
  float re=0.f, im=0.f;
  for(int my=0;my<16;my++){
    int ky = my<8 ? my : my+16;
    int k = (ky*y)&31; float cs=twc[k], sn=tws[k];
    float a = Ar[(size_t)((x*16+my)*8+kz)*64+c];
    float b = Ai[(size_t)((x*16+my)*8+kz)*64+c];
    re += a*cs - b*sn;
    im += a*sn + b*cs;
  }
  Fr[idx]=re; Fi[idx]=im;
}

__global__ void k_fz_inv_skip(const float* __restrict__ G2re, const float* __restrict__ G2im,
    const float* __restrict__ h, const float* __restrict__ twc, const float* __restrict__ tws,
    const float* __restrict__ sw, float* __restrict__ a_out)
{
  __shared__ float hrow[4][64];
  int t = threadIdx.x; int c = t&63; int pl = t>>6;
  int p = blockIdx.x*4 + pl;
  int z = p & 31; int xy = p >> 5;
  hrow[pl][c] = h[(size_t)p*64 + c];
  __syncthreads();
  const float* gr = G2re + (size_t)(xy*8)*64 + c;
  const float* gi = G2im + (size_t)(xy*8)*64 + c;
  float acc = gr[0];
  #pragma unroll
  for(int kz=1;kz<8;kz++){
    int k = (kz*z)&31;
    acc += 2.f*(gr[(size_t)kz*64]*twc[k] - gi[(size_t)kz*64]*tws[k]);
  }
  float vfno = acc * (1.f/32768.f);
  float vskip = 0.f;
  for(int i=0;i<64;i++) vskip = fmaf(hrow[pl][i], sw[i*64+c], vskip);
  a_out[(size_t)p*64+c] = gelu_f(vfno + vskip);
}

// -------- projection --------
__global__ __launch_bounds__(256) void k_proj(const float* __restrict__ outev,
    const float* __restrict__ pw0, const float* __restrict__ pb0,
    const float* __restrict__ pw1, const float* __restrict__ pb1,
    float* __restrict__ outp)
{
  __shared__ float msg[8][64];
  __shared__ float red[8][4];
  int t = threadIdx.x; int q0 = blockIdx.x*8;
  for(int w=t; w<512; w+=256){
    int qq=w>>6, o=w&63; int q=q0+qq;
    msg[qq][o] = (q<N_OUT) ? outev[(size_t)q*64+o] : 0.f;
  }
  __syncthreads();
  float p[8]; float bb = pb0[t];
  #pragma unroll
  for(int qq=0;qq<8;qq++) p[qq]=bb;
  for(int o=0;o<64;o++){
    float wv = pw0[o*256+t];
    #pragma unroll
    for(int qq=0;qq<8;qq++) p[qq] = fmaf(msg[qq][o], wv, p[qq]);
  }
  float w1v = pw1[t];
  int lane = t & 63, wid = t >> 6;
  #pragma unroll
  for(int qq=0;qq<8;qq++){
    float v = gelu_f(p[qq]) * w1v;
    for(int d=32; d>=1; d>>=1) v += __shfl_down(v, d, 64);
    if(lane==0) red[qq][wid]=v;
  }
  __syncthreads();
  if(t<8){
    int q = q0+t;
    if(q<N_OUT) outp[q] = red[t][0]+red[t][1]+red[t][2]+red[t][3] + pb1[0];
  }
}

// ==================== host ====================
extern "C" void kernel_launch(void* const* d_in, const int* in_sizes, int n_in,
                              void* d_out, int out_size, void* d_ws, size_t ws_size,
                              hipStream_t stream)
{
  (void)in_sizes; (void)n_in; (void)out_size; (void)ws_size;
  const float* geom = (const float*)d_in[0];
  const float* latq = (const float*)d_in[1];
  const float* outq = (const float*)d_in[2];
  const float* xin  = (const float*)d_in[3];
  const float* ilw  = (const float*)d_in[4];
  const float* ilb  = (const float*)d_in[5];
  const float* ikw0 = (const float*)d_in[6];
  const float* ikb0 = (const float*)d_in[7];
  const float* ikw1 = (const float*)d_in[8];
  const float* ikb1 = (const float*)d_in[9];
  const float* ikw2 = (const float*)d_in[10];
  const float* ikb2 = (const float*)d_in[11];
  const float* ikw3 = (const float*)d_in[12];
  const float* ikb3 = (const float*)d_in[13];
  const float* lw0  = (const float*)d_in[14];
  const float* lb0  = (const float*)d_in[15];
  const float* lw1  = (const float*)d_in[16];
  const float* lb1  = (const float*)d_in[17];
  const float* specw= (const float*)d_in[18];
  const float* skw  = (const float*)d_in[19];
  const float* gw   = (const float*)d_in[20];
  const float* gb   = (const float*)d_in[21];
  const float* cw0  = (const float*)d_in[22];
  const float* cb0  = (const float*)d_in[23];
  const float* cw1  = (const float*)d_in[24];
  const float* cb1  = (const float*)d_in[25];
  const float* okw0 = (const float*)d_in[26];
  const float* okb0 = (const float*)d_in[27];
  const float* okw1 = (const float*)d_in[28];
  const float* okb1 = (const float*)d_in[29];
  const float* okw2 = (const float*)d_in[30];
  const float* okb2 = (const float*)d_in[31];
  const float* pw0  = (const float*)d_in[32];
  const float* pb0  = (const float*)d_in[33];
  const float* pw1  = (const float*)d_in[34];
  const float* pb1  = (const float*)d_in[35];
  const int* iidx = (const int*)d_in[36];
  const int* oidx = (const int*)d_in[37];
  float* outp = (float*)d_out;
  float* ws = (float*)d_ws;

  size_t off = 0;
  float* F_IN = ws + off; off += (size_t)N_IN*64;
  float* AIN  = ws + off; off += (size_t)N_IN*80;
  float* BIN_ = ws + off; off += (size_t)N_LQ*80;
  float* AOUT = ws + off; off += (size_t)N_LQ*512;
  float* BOUT = ws + off; off += (size_t)N_OUT*512;
  float* HBUF = ws + off; off += (size_t)N_LQ*64;
  float* ABUF = ws + off; off += (size_t)N_LQ*64;
  float* FZr = ws+off; off+=524288; float* FZi = ws+off; off+=524288;
  float* FYr = ws+off; off+=262144; float* FYi = ws+off; off+=262144;
  float* FXr = ws+off; off+=131072; float* FXi = ws+off; off+=131072;
  float* GMr = ws+off; off+=131072; float* GMi = ws+off; off+=131072;
  float* G1r = ws+off; off+=262144; float* G1i = ws+off; off+=262144;
  float* G2r = ws+off; off+=524288; float* G2i = ws+off; off+=524288;
  float* OUTEV = ws+off; off += (size_t)N_OUT*64;
  float* TWC = ws+off; off+=32; float* TWS = ws+off; off+=32;
  off = (off + 3) & ~(size_t)3;
  _Float16* P = (_Float16*)(ws + off);
  _Float16 *W1h = P,          *W1l = P+131072;
  _Float16 *W2h = P+262144,   *W2l = P+278528;
  _Float16 *I1h = P+294912,   *I1l = P+301312;
  _Float16 *I2h = P+307712,   *I2l = P+314112;
  _Float16 *I3h = P+320512,   *I3l = P+325632;

  k_twiddle<<<1, 64, 0, stream>>>(TWC, TWS);
  k_prep<<<512, 256, 0, stream>>>(okw1, okw2, ikw1, ikw2, ikw3,
                                  W1h, W1l, W2h, W2l, I1h, I1l, I2h, I2l, I3h, I3l);
  k_lift_in<<<(N_IN*64)/256, 256, 0, stream>>>(xin, ilw, ilb, F_IN);
  k_embed_partial<80,false><<<N_IN/8, 256, 0, stream>>>(geom, N_IN, ikw0, 0, (const float*)nullptr, AIN);
  k_embed_partial<80,true ><<<N_LQ/8, 256, 0, stream>>>(latq, N_LQ, ikw0, 96, ikb0, BIN_);
  k_embed_partial<512,false><<<N_LQ/8, 256, 0, stream>>>(latq, N_LQ, okw0, 0, (const float*)nullptr, AOUT);
  k_embed_partial<512,true ><<<(N_OUT+7)/8, 256, 0, stream>>>(outq, N_OUT, okw0, 96, okb0, BOUT);

  hipMemsetAsync(HBUF, 0, (size_t)N_LQ*64*sizeof(float), stream);
  k_gino<<<(N_LQ*KNB)/64, 256, 0, stream>>>(AIN, BIN_, F_IN, iidx,
                                            I1h, I1l, ikb1, I2h, I2l, ikb2, I3h, I3l, ikb3, HBUF);
  k_mlp_plain<<<N_LQ/16, 256, 0, stream>>>(HBUF, lw0, lb0, lw1, lb1, HBUF);

  for(int l=0;l<4;l++){
    k_fz_fwd<<<2048,256,0,stream>>>(HBUF, TWC, TWS, FZr, FZi);
    k_fy_fwd<<<1024,256,0,stream>>>(FZr, FZi, TWC, TWS, FYr, FYi);
    k_fx_fwd<<<512,256,0,stream>>>(FYr, FYi, TWC, TWS, FXr, FXi);
    k_smm<<<512,256,0,stream>>>(FXr, FXi, specw + (size_t)l*16777216, GMr, GMi);
    k_fx_inv<<<1024,256,0,stream>>>(GMr, GMi, TWC, TWS, G1r, G1i);
    k_fy_inv<<<2048,256,0,stream>>>(G1r, G1i, TWC, TWS, G2r, G2i);
    k_fz_inv_skip<<<8192,256,0,stream>>>(G2r, G2i, HBUF, TWC, TWS, skw + (size_t)l*4096, ABUF);
    k_mlp_gated<<<N_LQ/16,256,0,stream>>>(ABUF, cw0 + (size_t)l*8192, cb0 + l*128,
                                          cw1 + (size_t)l*8192, cb1 + l*64,
                                          gw + l*64, gb + l*64, HBUF);
  }

  hipMemsetAsync(OUTEV, 0, (size_t)N_OUT*64*sizeof(float), stream);
  k_ogno<<<(N_OUT*KNB + 63)/64, 256, 0, stream>>>(AOUT, BOUT, oidx,
                                                  W1h, W1l, okb1, W2h, W2l, okb2,
                                                  HBUF, OUTEV, N_OUT*KNB);
  k_proj<<<(N_OUT+7)/8, 256, 0, stream>>>(OUTEV, pw0, pb0, pw1, pb1, outp);
}